// Round 2
// baseline (1225.958 us; speedup 1.0000x reference)
//
#include <hip/hip_runtime.h>
#include <hip/hip_bf16.h>
#include <math.h>

// Problem constants
#define NH   64     // b*H heads
#define DKC  64     // dim per head
#define MM   4096   // x*y
#define CC   256    // img channels
#define RRN  127    // 2L-1

typedef __hip_bfloat16 bf16;
__device__ __forceinline__ float b2f(bf16 x) { return __bfloat162float(x); }
__device__ __forceinline__ bf16 f2b(float x) { return __float2bfloat16(x); }

// ---------------------------------------------------------------------------
// K1: qkv = W(1536x256) @ img_b(256x4096), routed into bf16 q/k/v [n][d][m]
// grid (64 m-tiles, 24 o-tiles, 8 b), block (16,16)
// ---------------------------------------------------------------------------
__global__ __launch_bounds__(256) void k_qkv(const float* __restrict__ img, const float* __restrict__ w,
                                             bf16* __restrict__ q, bf16* __restrict__ kk, bf16* __restrict__ v) {
  const int b = blockIdx.z;
  const int o0 = blockIdx.y * 64;
  const int m0 = blockIdx.x * 64;
  const int tx = threadIdx.x, ty = threadIdx.y;
  const int tid = ty * 16 + tx;
  __shared__ float As[16][65];  // As[k][o]
  __shared__ float Bs[16][65];  // Bs[k][m]
  float acc[4][4] = {};
  const float* imgb = img + (size_t)b * CC * MM;
  for (int k0 = 0; k0 < CC; k0 += 16) {
#pragma unroll
    for (int l = 0; l < 4; ++l) {
      int e = tid + l * 256;
      int i = e >> 4, kj = e & 15;
      As[kj][i] = w[(size_t)(o0 + i) * CC + k0 + kj];
      int kj2 = e >> 6, j = e & 63;
      Bs[kj2][j] = imgb[(size_t)(k0 + kj2) * MM + m0 + j];
    }
    __syncthreads();
#pragma unroll
    for (int kj = 0; kj < 16; ++kj) {
      float a[4], bbv[4];
#pragma unroll
      for (int u = 0; u < 4; ++u) a[u] = As[kj][ty * 4 + u];
#pragma unroll
      for (int u = 0; u < 4; ++u) bbv[u] = Bs[kj][tx * 4 + u];
#pragma unroll
      for (int u = 0; u < 4; ++u)
#pragma unroll
        for (int w2 = 0; w2 < 4; ++w2) acc[u][w2] += a[u] * bbv[w2];
    }
    __syncthreads();
  }
#pragma unroll
  for (int u = 0; u < 4; ++u) {
    int oo = o0 + ty * 4 + u;
    bf16* dst;
    if (oo < 512) { dst = q; }
    else if (oo < 1024) { dst = kk; oo -= 512; }
    else { dst = v; oo -= 1024; }
    bf16* p = dst + ((size_t)b * 512 + oo) * MM + m0 + tx * 4;
#pragma unroll
    for (int w2 = 0; w2 < 4; ++w2) p[w2] = f2b(acc[u][w2]);
  }
}

// ---------------------------------------------------------------------------
// K2: in-place softmax over m=4096 per (n,d) row. grid 4096, block 256
// ---------------------------------------------------------------------------
__global__ __launch_bounds__(256) void k_softmax(bf16* __restrict__ kk) {
  const size_t row = blockIdx.x;
  bf16* p = kk + row * (size_t)MM;
  const int t = threadIdx.x;
  __shared__ float sred[4];
  float mx = -1e30f;
  for (int i = t; i < MM; i += 256) mx = fmaxf(mx, b2f(p[i]));
#pragma unroll
  for (int off = 32; off; off >>= 1) mx = fmaxf(mx, __shfl_down(mx, off));
  if ((t & 63) == 0) sred[t >> 6] = mx;
  __syncthreads();
  mx = fmaxf(fmaxf(sred[0], sred[1]), fmaxf(sred[2], sred[3]));
  __syncthreads();
  float s = 0.f;
  for (int i = t; i < MM; i += 256) { float e = expf(b2f(p[i]) - mx); p[i] = f2b(e); s += e; }
#pragma unroll
  for (int off = 32; off; off >>= 1) s += __shfl_down(s, off);
  if ((t & 63) == 0) sred[t >> 6] = s;
  __syncthreads();
  s = sred[0] + sred[1] + sred[2] + sred[3];
  const float inv = 1.0f / s;
  for (int i = t; i < MM; i += 256) p[i] = f2b(b2f(p[i]) * inv);
}

// ---------------------------------------------------------------------------
// K3a: partial context[n,d,e] = sum_m k[n,d,m]*v[n,e,m], m-chunked by 512
// grid (8 chunks, 64 n), block (16,16)
// ---------------------------------------------------------------------------
__global__ __launch_bounds__(256) void k_ctx_part(const bf16* __restrict__ kk, const bf16* __restrict__ v,
                                                  float* __restrict__ part) {
  const int ch = blockIdx.x, n = blockIdx.y;
  const int tx = threadIdx.x, ty = threadIdx.y;
  const int tid = ty * 16 + tx;
  __shared__ float Ks[64][65];
  __shared__ float Vs[64][65];
  float acc[4][4] = {};
  const bf16* kp = kk + (size_t)n * DKC * MM;
  const bf16* vp = v + (size_t)n * DKC * MM;
  for (int m0 = ch * 512; m0 < ch * 512 + 512; m0 += 64) {
#pragma unroll
    for (int l = 0; l < 16; ++l) {
      int e = tid + l * 256;
      int d = e >> 6, j = e & 63;
      Ks[d][j] = b2f(kp[(size_t)d * MM + m0 + j]);
      Vs[d][j] = b2f(vp[(size_t)d * MM + m0 + j]);
    }
    __syncthreads();
#pragma unroll
    for (int j = 0; j < 64; ++j) {
      float a[4], bbv[4];
#pragma unroll
      for (int u = 0; u < 4; ++u) a[u] = Ks[ty * 4 + u][j];
#pragma unroll
      for (int u = 0; u < 4; ++u) bbv[u] = Vs[tx * 4 + u][j];
#pragma unroll
      for (int u = 0; u < 4; ++u)
#pragma unroll
        for (int w2 = 0; w2 < 4; ++w2) acc[u][w2] += a[u] * bbv[w2];
    }
    __syncthreads();
  }
#pragma unroll
  for (int u = 0; u < 4; ++u)
#pragma unroll
    for (int w2 = 0; w2 < 4; ++w2)
      part[((size_t)ch * NH + n) * 4096 + (ty * 4 + u) * 64 + tx * 4 + w2] = acc[u][w2];
}

// K3b: reduce 8 partials. grid 1024, block 256
__global__ __launch_bounds__(256) void k_ctx_red(const float* __restrict__ part, float* __restrict__ ctx) {
  const int idx = blockIdx.x * 256 + threadIdx.x;  // < 262144
  float s = 0.f;
#pragma unroll
  for (int c = 0; c < 8; ++c) s += part[(size_t)c * 262144 + idx];
  ctx[idx] = s;
}

// ---------------------------------------------------------------------------
// K4: content[n,e,m] = sum_d ctx[n,d,e]*q[n,d,m]. grid (64 mt, 64 n)
// ---------------------------------------------------------------------------
__global__ __launch_bounds__(256) void k_content(const float* __restrict__ ctx, const bf16* __restrict__ q,
                                                 bf16* __restrict__ content) {
  const int m0 = blockIdx.x * 64, n = blockIdx.y;
  const int tx = threadIdx.x, ty = threadIdx.y;
  const int tid = ty * 16 + tx;
  __shared__ float Cs[64][65];  // Cs[d][e]
  __shared__ float Qs[64][65];  // Qs[d][j]
  const float* cn = ctx + (size_t)n * 4096;
  const bf16* qn = q + (size_t)n * DKC * MM;
#pragma unroll
  for (int l = 0; l < 16; ++l) {
    int e = tid + l * 256;
    int d = e >> 6, j = e & 63;
    Cs[d][j] = cn[e];
    Qs[d][j] = b2f(qn[(size_t)d * MM + m0 + j]);
  }
  __syncthreads();
  float acc[4][4] = {};
#pragma unroll 8
  for (int d = 0; d < 64; ++d) {
    float a[4], bbv[4];
#pragma unroll
    for (int u = 0; u < 4; ++u) a[u] = Cs[d][ty * 4 + u];
#pragma unroll
    for (int u = 0; u < 4; ++u) bbv[u] = Qs[d][tx * 4 + u];
#pragma unroll
    for (int u = 0; u < 4; ++u)
#pragma unroll
      for (int w2 = 0; w2 < 4; ++w2) acc[u][w2] += a[u] * bbv[w2];
  }
#pragma unroll
  for (int u = 0; u < 4; ++u)
#pragma unroll
    for (int w2 = 0; w2 < 4; ++w2)
      content[(size_t)n * DKC * MM + (size_t)(ty * 4 + u) * MM + m0 + tx * 4 + w2] = f2b(acc[u][w2]);
}

// ---------------------------------------------------------------------------
// K5: fused rel-row path per (n, y):  LDS phase-overlay, 49.6 KB total
//   Ss[i][x] = sum_d q[n,d,x,y]*rel_rows[i-x+63,d]
//   Yh[n,e,x,y] = sum_i v[n,e,i,y]*Ss[i][x]
// grid (64 y, 64 n), block (16,16)
// ---------------------------------------------------------------------------
__global__ __launch_bounds__(256) void k_relrow(const bf16* __restrict__ q, const bf16* __restrict__ v,
                                                const float* __restrict__ relr, bf16* __restrict__ yh) {
  const int yy = blockIdx.x, n = blockIdx.y;
  const int tx = threadIdx.x, ty = threadIdx.y;
  const int tid = ty * 16 + tx;
  __shared__ float RV[RRN * 65];  // phase1: Rr[r][d] ; phase2: Vs[e][i]
  __shared__ float QS[64 * 65];   // phase1: Qs[d][x] ; phase2: Ss[i][x]
  const size_t nb = (size_t)n * DKC * MM;
  // prefetch phase-2 (v) data into registers
  bf16 vreg[16];
#pragma unroll
  for (int l = 0; l < 16; ++l) {
    int e = tid + l * 256;
    vreg[l] = v[nb + (size_t)(e >> 6) * MM + (e & 63) * 64 + yy];
  }
  for (int e = tid; e < RRN * 64; e += 256) RV[(e >> 6) * 65 + (e & 63)] = relr[e];
#pragma unroll
  for (int l = 0; l < 16; ++l) {
    int e = tid + l * 256;
    QS[(e >> 6) * 65 + (e & 63)] = b2f(q[nb + (size_t)(e >> 6) * MM + (e & 63) * 64 + yy]);
  }
  __syncthreads();
  float acc[4][4] = {};
#pragma unroll 8
  for (int d = 0; d < 64; ++d) {
    float qv[4];
#pragma unroll
    for (int w2 = 0; w2 < 4; ++w2) qv[w2] = QS[d * 65 + tx * 4 + w2];
#pragma unroll
    for (int u = 0; u < 4; ++u) {
      const int i = ty * 4 + u;
#pragma unroll
      for (int w2 = 0; w2 < 4; ++w2) acc[u][w2] += qv[w2] * RV[(i - (tx * 4 + w2) + 63) * 65 + d];
    }
  }
  __syncthreads();
  // overlay: Ss -> QS, Vs -> RV
#pragma unroll
  for (int u = 0; u < 4; ++u)
#pragma unroll
    for (int w2 = 0; w2 < 4; ++w2) QS[(ty * 4 + u) * 65 + tx * 4 + w2] = acc[u][w2];
#pragma unroll
  for (int l = 0; l < 16; ++l) {
    int e = tid + l * 256;
    RV[(e >> 6) * 65 + (e & 63)] = b2f(vreg[l]);
  }
  __syncthreads();
  float acc2[4][4] = {};
#pragma unroll 8
  for (int i = 0; i < 64; ++i) {
    float sv[4], vv[4];
#pragma unroll
    for (int w2 = 0; w2 < 4; ++w2) sv[w2] = QS[i * 65 + tx * 4 + w2];
#pragma unroll
    for (int u = 0; u < 4; ++u) vv[u] = RV[(ty * 4 + u) * 65 + i];
#pragma unroll
    for (int u = 0; u < 4; ++u)
#pragma unroll
      for (int w2 = 0; w2 < 4; ++w2) acc2[u][w2] += vv[u] * sv[w2];
  }
#pragma unroll
  for (int u = 0; u < 4; ++u)
#pragma unroll
    for (int w2 = 0; w2 < 4; ++w2)
      yh[nb + (size_t)(ty * 4 + u) * MM + (tx * 4 + w2) * 64 + yy] = f2b(acc2[u][w2]);
}

// ---------------------------------------------------------------------------
// K6a: BN partial stats per (e, n-group of 8). grid (64, 8), block 256
// ---------------------------------------------------------------------------
__global__ __launch_bounds__(256) void k_bnpart(const bf16* __restrict__ yh, float* __restrict__ ps,
                                                float* __restrict__ ps2) {
  const int e = blockIdx.x, g = blockIdx.y;
  const int t = threadIdx.x;
  float s = 0.f, s2 = 0.f;
  for (int nn = g * 8; nn < g * 8 + 8; ++nn) {
    const bf16* p = yh + (size_t)nn * DKC * MM + (size_t)e * MM;
    for (int i = t; i < MM; i += 256) { float x = b2f(p[i]); s += x; s2 += x * x; }
  }
#pragma unroll
  for (int off = 32; off; off >>= 1) { s += __shfl_down(s, off); s2 += __shfl_down(s2, off); }
  __shared__ float r1[4], r2[4];
  if ((t & 63) == 0) { r1[t >> 6] = s; r2[t >> 6] = s2; }
  __syncthreads();
  if (t == 0) {
    ps[e * 8 + g] = r1[0] + r1[1] + r1[2] + r1[3];
    ps2[e * 8 + g] = r2[0] + r2[1] + r2[2] + r2[3];
  }
}

// K6b: finalize BN stats. grid 1, block 64
__global__ __launch_bounds__(64) void k_bnfin(const float* __restrict__ ps, const float* __restrict__ ps2,
                                              float* __restrict__ mu, float* __restrict__ rs) {
  const int e = threadIdx.x;
  float S = 0.f, S2 = 0.f;
#pragma unroll
  for (int g = 0; g < 8; ++g) { S += ps[e * 8 + g]; S2 += ps2[e * 8 + g]; }
  const float invN = 1.0f / (NH * (float)MM);
  float m = S * invN;
  float var = S2 * invN - m * m;
  mu[e] = m;
  rs[e] = 1.0f / sqrtf(var + 1e-5f);
}

// ---------------------------------------------------------------------------
// K7: fused rel-col path per (n, x):  LDS phase-overlay
//   Ss[i][y] = sum_d q[n,d,x,y]*rel_cols[i-y+63,d]
//   out[n,e,x,y] += sum_i BN(Yh[n,e,x,i])*Ss[i][y]   (accumulates into content)
// grid (64 x, 64 n), block (16,16)
// ---------------------------------------------------------------------------
__global__ __launch_bounds__(256) void k_relcol(const bf16* __restrict__ q, const bf16* __restrict__ yh,
                                                const float* __restrict__ relc, const float* __restrict__ mu,
                                                const float* __restrict__ rs, const float* __restrict__ gamma,
                                                const float* __restrict__ beta, bf16* __restrict__ outc) {
  const int xx = blockIdx.x, n = blockIdx.y;
  const int tx = threadIdx.x, ty = threadIdx.y;
  const int tid = ty * 16 + tx;
  __shared__ float RV[RRN * 65];  // phase1: Rc[r][d] ; phase2: Ys[e][i]
  __shared__ float QS[64 * 65];   // phase1: Qs[d][y] ; phase2: Ss[i][y]
  const size_t nb = (size_t)n * DKC * MM;
  // prefetch phase-2 (yh) data into registers
  bf16 yreg[16];
#pragma unroll
  for (int l = 0; l < 16; ++l) {
    int e = tid + l * 256;
    yreg[l] = yh[nb + (size_t)(e >> 6) * MM + xx * 64 + (e & 63)];
  }
  for (int e = tid; e < RRN * 64; e += 256) RV[(e >> 6) * 65 + (e & 63)] = relc[e];
#pragma unroll
  for (int l = 0; l < 16; ++l) {
    int e = tid + l * 256;
    QS[(e >> 6) * 65 + (e & 63)] = b2f(q[nb + (size_t)(e >> 6) * MM + xx * 64 + (e & 63)]);
  }
  __syncthreads();
  float acc[4][4] = {};
#pragma unroll 8
  for (int d = 0; d < 64; ++d) {
    float qv[4];
#pragma unroll
    for (int w2 = 0; w2 < 4; ++w2) qv[w2] = QS[d * 65 + tx * 4 + w2];
#pragma unroll
    for (int u = 0; u < 4; ++u) {
      const int i = ty * 4 + u;
#pragma unroll
      for (int w2 = 0; w2 < 4; ++w2) acc[u][w2] += qv[w2] * RV[(i - (tx * 4 + w2) + 63) * 65 + d];
    }
  }
  __syncthreads();
  // overlay: Ss -> QS, Ys(BN applied) -> RV
#pragma unroll
  for (int u = 0; u < 4; ++u)
#pragma unroll
    for (int w2 = 0; w2 < 4; ++w2) QS[(ty * 4 + u) * 65 + tx * 4 + w2] = acc[u][w2];
#pragma unroll
  for (int l = 0; l < 16; ++l) {
    int e = tid + l * 256;
    int ee = e >> 6;
    RV[ee * 65 + (e & 63)] = (b2f(yreg[l]) - mu[ee]) * rs[ee] * gamma[ee] + beta[ee];
  }
  __syncthreads();
  float acc2[4][4] = {};
#pragma unroll 8
  for (int i = 0; i < 64; ++i) {
    float sv[4], yv[4];
#pragma unroll
    for (int w2 = 0; w2 < 4; ++w2) sv[w2] = QS[i * 65 + tx * 4 + w2];
#pragma unroll
    for (int u = 0; u < 4; ++u) yv[u] = RV[(ty * 4 + u) * 65 + i];
#pragma unroll
    for (int u = 0; u < 4; ++u)
#pragma unroll
      for (int w2 = 0; w2 < 4; ++w2) acc2[u][w2] += yv[u] * sv[w2];
  }
#pragma unroll
  for (int u = 0; u < 4; ++u)
#pragma unroll
    for (int w2 = 0; w2 < 4; ++w2) {
      size_t a = nb + (size_t)(ty * 4 + u) * MM + xx * 64 + tx * 4 + w2;
      outc[a] = f2b(b2f(outc[a]) + acc2[u][w2]);
    }
}

// ---------------------------------------------------------------------------
// K8: final = Wout(256x512) @ combined_b(512x4096) + bias. grid (64 mt, 4 ot, 8 b)
// ---------------------------------------------------------------------------
__global__ __launch_bounds__(256) void k_final(const bf16* __restrict__ src, const float* __restrict__ wout,
                                               const float* __restrict__ bout, float* __restrict__ dout) {
  const int b = blockIdx.z;
  const int o0 = blockIdx.y * 64;
  const int m0 = blockIdx.x * 64;
  const int tx = threadIdx.x, ty = threadIdx.y;
  const int tid = ty * 16 + tx;
  __shared__ float As[16][65];
  __shared__ float Bs[16][65];
  float acc[4][4] = {};
  const bf16* sb = src + (size_t)b * 512 * MM;
  for (int k0 = 0; k0 < 512; k0 += 16) {
#pragma unroll
    for (int l = 0; l < 4; ++l) {
      int e = tid + l * 256;
      int i = e >> 4, kj = e & 15;
      As[kj][i] = wout[(size_t)(o0 + i) * 512 + k0 + kj];
      int kj2 = e >> 6, j = e & 63;
      Bs[kj2][j] = b2f(sb[(size_t)(k0 + kj2) * MM + m0 + j]);
    }
    __syncthreads();
#pragma unroll
    for (int kj = 0; kj < 16; ++kj) {
      float a[4], bbv[4];
#pragma unroll
      for (int u = 0; u < 4; ++u) a[u] = As[kj][ty * 4 + u];
#pragma unroll
      for (int u = 0; u < 4; ++u) bbv[u] = Bs[kj][tx * 4 + u];
#pragma unroll
      for (int u = 0; u < 4; ++u)
#pragma unroll
        for (int w2 = 0; w2 < 4; ++w2) acc[u][w2] += a[u] * bbv[w2];
    }
    __syncthreads();
  }
#pragma unroll
  for (int u = 0; u < 4; ++u) {
    const float bias = bout[o0 + ty * 4 + u];
#pragma unroll
    for (int w2 = 0; w2 < 4; ++w2)
      dout[((size_t)b * 256 + o0 + ty * 4 + u) * MM + m0 + tx * 4 + w2] = acc[u][w2] + bias;
  }
}

// ---------------------------------------------------------------------------
extern "C" void kernel_launch(void* const* d_in, const int* in_sizes, int n_in,
                              void* d_out, int out_size, void* d_ws, size_t ws_size,
                              hipStream_t stream) {
  const float* img = (const float*)d_in[0];
  const float* w_qkv = (const float*)d_in[1];
  const float* w_out = (const float*)d_in[2];
  const float* b_out = (const float*)d_in[3];
  const float* rel_rows = (const float*)d_in[4];
  const float* rel_cols = (const float*)d_in[5];
  const float* gamma = (const float*)d_in[6];
  const float* beta = (const float*)d_in[7];
  float* out = (float*)d_out;

  const size_t SZ = (size_t)NH * DKC * MM;  // 16,777,216 elements
  bf16* q = (bf16*)d_ws;          // SZ bf16
  bf16* kbuf = q + SZ;            // SZ bf16: k, later reused as yh
  bf16* vbuf = kbuf + SZ;         // SZ bf16: v, later reused as content
  float* fws = (float*)(vbuf + SZ);
  float* ctxp = fws;              // 2,097,152 f32
  float* ctx = ctxp + 2097152;    // 262,144 f32
  float* ps = ctx + 262144;       // 512
  float* ps2 = ps + 512;          // 512
  float* mu = ps2 + 512;          // 64
  float* rs = mu + 64;            // 64
  // total ~110.1 MB

  k_qkv<<<dim3(64, 24, 8), dim3(16, 16), 0, stream>>>(img, w_qkv, q, kbuf, vbuf);
  k_softmax<<<4096, 256, 0, stream>>>(kbuf);
  k_ctx_part<<<dim3(8, 64), dim3(16, 16), 0, stream>>>(kbuf, vbuf, ctxp);
  k_ctx_red<<<1024, 256, 0, stream>>>(ctxp, ctx);
  // k dead -> kbuf becomes yh
  k_relrow<<<dim3(64, 64), dim3(16, 16), 0, stream>>>(q, vbuf, rel_rows, kbuf);
  k_bnpart<<<dim3(64, 8), 256, 0, stream>>>(kbuf, ps, ps2);
  k_bnfin<<<1, 64, 0, stream>>>(ps, ps2, mu, rs);
  // v dead -> vbuf becomes content
  k_content<<<dim3(64, 64), dim3(16, 16), 0, stream>>>(ctx, q, vbuf);
  k_relcol<<<dim3(64, 64), dim3(16, 16), 0, stream>>>(q, kbuf, rel_cols, mu, rs, gamma, beta, vbuf);
  k_final<<<dim3(64, 4, 8), dim3(16, 16), 0, stream>>>(vbuf, w_out, b_out, out);
}

// Round 3
// 801.744 us; speedup vs baseline: 1.5291x; 1.5291x over previous
//
#include <hip/hip_runtime.h>
#include <hip/hip_bf16.h>
#include <math.h>

// Problem constants
#define NH   64     // b*H heads
#define DKC  64     // dim per head
#define MM   4096   // x*y
#define CC   256    // img channels
#define RRN  127    // 2L-1

typedef __hip_bfloat16 bf16;
__device__ __forceinline__ float b2f(bf16 x) { return __bfloat162float(x); }
__device__ __forceinline__ bf16 f2b(float x) { return __float2bfloat16(x); }

typedef short bf16x8 __attribute__((ext_vector_type(8)));
typedef float f32x4 __attribute__((ext_vector_type(4)));

#define AS1 __attribute__((address_space(1)))
#define AS3 __attribute__((address_space(3)))
#define GLOAD16(gp, lp) __builtin_amdgcn_global_load_lds((const AS1 void*)(gp), (AS3 void*)(lp), 16, 0, 0)

// ---------------------------------------------------------------------------
// K0a: convert w_qkv fp32 -> bf16 (row-major [1536][256], K-contiguous)
// ---------------------------------------------------------------------------
__global__ __launch_bounds__(256) void k_cvt_w(const float* __restrict__ w, bf16* __restrict__ wb) {
  const int i = blockIdx.x * 256 + threadIdx.x;  // grid covers 393216
  wb[i] = f2b(w[i]);
}

// ---------------------------------------------------------------------------
// K0b: img fp32 [8][256][4096] -> bf16 imgT [8][4096][256] (transpose, K-contig)
// grid (64 mtiles, 4 ctiles, 8 b), block 256
// ---------------------------------------------------------------------------
__global__ __launch_bounds__(256) void k_timg(const float* __restrict__ img, bf16* __restrict__ imgT) {
  const int b = blockIdx.z, c0 = blockIdx.y * 64, m0 = blockIdx.x * 64;
  const int tid = threadIdx.x;
  __shared__ bf16 T[64][65];
  const float* ib = img + ((size_t)b * CC + c0) * MM + m0;
#pragma unroll
  for (int l = 0; l < 16; ++l) {
    int e = tid + l * 256;
    int cc = e >> 6, mm = e & 63;
    T[cc][mm] = f2b(ib[(size_t)cc * MM + mm]);
  }
  __syncthreads();
  bf16* ob = imgT + ((size_t)b * MM + m0) * CC + c0;
#pragma unroll
  for (int l = 0; l < 16; ++l) {
    int e = tid + l * 256;
    int mm = e >> 6, cc = e & 63;
    ob[(size_t)mm * CC + cc] = T[cc][mm];
  }
}

// ---------------------------------------------------------------------------
// K1: MFMA qkv GEMM: out[o][m] = sum_c wb[o][c] * imgT[b][m][c]
// 128x128 tile, BK=64, 4 waves (2x2), 4x4 16x16x32 frags per wave.
// grid (32 mtiles, 12 otiles, 8 b), block 256. Routed into q/k/v [b][512][4096]
// ---------------------------------------------------------------------------
__global__ __launch_bounds__(256) void k_qkv(const bf16* __restrict__ wb, const bf16* __restrict__ imgT,
                                             bf16* __restrict__ q, bf16* __restrict__ kk, bf16* __restrict__ v) {
  const int bI = blockIdx.z;
  const int o0 = blockIdx.y * 128;
  const int m0 = blockIdx.x * 128;
  const int tid = threadIdx.x;
  const int lane = tid & 63, wid = tid >> 6;
  const int fr = lane & 15;        // A-row / B-col / D-col
  const int fq = lane >> 4;        // k-group / D-row-group
  const int wm = (wid >> 1) * 64, wn = (wid & 1) * 64;

  __shared__ __align__(16) short As[128 * 64];  // [row][k] bf16 bits
  __shared__ __align__(16) short Bs[128 * 64];  // [m-row][k]

  const bf16* iB = imgT + (size_t)bI * MM * CC;

  f32x4 acc[4][4];
#pragma unroll
  for (int mi = 0; mi < 4; ++mi)
#pragma unroll
    for (int ni = 0; ni < 4; ++ni) acc[mi][ni] = (f32x4){0.f, 0.f, 0.f, 0.f};

  const int srow = lane >> 3;        // 0..7 within chunk
  const int skc = (lane & 7) * 8;    // bf16 k offset within row

  for (int kt = 0; kt < 4; ++kt) {
    const int k0 = kt * 64;
    // stage A (16KB) + B (16KB): 16 chunks of 1KB each; wave w -> chunks 4w..4w+3
#pragma unroll
    for (int cc = 0; cc < 4; ++cc) {
      const int c = wid * 4 + cc;
      const int r = c * 8 + srow;
      GLOAD16(wb + (size_t)(o0 + r) * CC + k0 + skc, &As[c * 512]);
      GLOAD16(iB + (size_t)(m0 + r) * CC + k0 + skc, &Bs[c * 512]);
    }
    __syncthreads();
    bf16x8 af[4][2], bfr[4][2];
#pragma unroll
    for (int mi = 0; mi < 4; ++mi)
#pragma unroll
      for (int kkk = 0; kkk < 2; ++kkk)
        af[mi][kkk] = *(const bf16x8*)&As[(wm + mi * 16 + fr) * 64 + kkk * 32 + fq * 8];
#pragma unroll
    for (int ni = 0; ni < 4; ++ni)
#pragma unroll
      for (int kkk = 0; kkk < 2; ++kkk)
        bfr[ni][kkk] = *(const bf16x8*)&Bs[(wn + ni * 16 + fr) * 64 + kkk * 32 + fq * 8];
#pragma unroll
    for (int mi = 0; mi < 4; ++mi)
#pragma unroll
      for (int ni = 0; ni < 4; ++ni)
#pragma unroll
        for (int kkk = 0; kkk < 2; ++kkk)
          acc[mi][ni] = __builtin_amdgcn_mfma_f32_16x16x32_bf16(af[mi][kkk], bfr[ni][kkk], acc[mi][ni], 0, 0, 0);
    __syncthreads();
  }

  // epilogue: D[row=o][col=m]; row=(l>>4)*4+r, col=l&15 per fragment
#pragma unroll
  for (int mi = 0; mi < 4; ++mi) {
#pragma unroll
    for (int ni = 0; ni < 4; ++ni) {
      const int mcol = m0 + wn + ni * 16 + fr;
#pragma unroll
      for (int r = 0; r < 4; ++r) {
        int oo = o0 + wm + mi * 16 + fq * 4 + r;
        bf16* dst;
        if (oo < 512) { dst = q; }
        else if (oo < 1024) { dst = kk; oo -= 512; }
        else { dst = v; oo -= 1024; }
        dst[((size_t)bI * 512 + oo) * MM + mcol] = f2b(acc[mi][ni][r]);
      }
    }
  }
}

// ---------------------------------------------------------------------------
// K2: in-place softmax over m=4096 per (n,d) row. grid 4096, block 256
// ---------------------------------------------------------------------------
__global__ __launch_bounds__(256) void k_softmax(bf16* __restrict__ kk) {
  const size_t row = blockIdx.x;
  bf16* p = kk + row * (size_t)MM;
  const int t = threadIdx.x;
  __shared__ float sred[4];
  float mx = -1e30f;
  for (int i = t; i < MM; i += 256) mx = fmaxf(mx, b2f(p[i]));
#pragma unroll
  for (int off = 32; off; off >>= 1) mx = fmaxf(mx, __shfl_down(mx, off));
  if ((t & 63) == 0) sred[t >> 6] = mx;
  __syncthreads();
  mx = fmaxf(fmaxf(sred[0], sred[1]), fmaxf(sred[2], sred[3]));
  __syncthreads();
  float s = 0.f;
  for (int i = t; i < MM; i += 256) { float e = expf(b2f(p[i]) - mx); p[i] = f2b(e); s += e; }
#pragma unroll
  for (int off = 32; off; off >>= 1) s += __shfl_down(s, off);
  if ((t & 63) == 0) sred[t >> 6] = s;
  __syncthreads();
  s = sred[0] + sred[1] + sred[2] + sred[3];
  const float inv = 1.0f / s;
  for (int i = t; i < MM; i += 256) p[i] = f2b(b2f(p[i]) * inv);
}

// ---------------------------------------------------------------------------
// K3a: partial context[n,d,e] = sum_m k[n,d,m]*v[n,e,m], m-chunked by 512
// grid (8 chunks, 64 n), block (16,16)
// ---------------------------------------------------------------------------
__global__ __launch_bounds__(256) void k_ctx_part(const bf16* __restrict__ kk, const bf16* __restrict__ v,
                                                  float* __restrict__ part) {
  const int ch = blockIdx.x, n = blockIdx.y;
  const int tx = threadIdx.x, ty = threadIdx.y;
  const int tid = ty * 16 + tx;
  __shared__ float Ks[64][65];
  __shared__ float Vs[64][65];
  float acc[4][4] = {};
  const bf16* kp = kk + (size_t)n * DKC * MM;
  const bf16* vp = v + (size_t)n * DKC * MM;
  for (int m0 = ch * 512; m0 < ch * 512 + 512; m0 += 64) {
#pragma unroll
    for (int l = 0; l < 16; ++l) {
      int e = tid + l * 256;
      int d = e >> 6, j = e & 63;
      Ks[d][j] = b2f(kp[(size_t)d * MM + m0 + j]);
      Vs[d][j] = b2f(vp[(size_t)d * MM + m0 + j]);
    }
    __syncthreads();
#pragma unroll
    for (int j = 0; j < 64; ++j) {
      float a[4], bbv[4];
#pragma unroll
      for (int u = 0; u < 4; ++u) a[u] = Ks[ty * 4 + u][j];
#pragma unroll
      for (int u = 0; u < 4; ++u) bbv[u] = Vs[tx * 4 + u][j];
#pragma unroll
      for (int u = 0; u < 4; ++u)
#pragma unroll
        for (int w2 = 0; w2 < 4; ++w2) acc[u][w2] += a[u] * bbv[w2];
    }
    __syncthreads();
  }
#pragma unroll
  for (int u = 0; u < 4; ++u)
#pragma unroll
    for (int w2 = 0; w2 < 4; ++w2)
      part[((size_t)ch * NH + n) * 4096 + (ty * 4 + u) * 64 + tx * 4 + w2] = acc[u][w2];
}

// K3b: reduce 8 partials. grid 1024, block 256
__global__ __launch_bounds__(256) void k_ctx_red(const float* __restrict__ part, float* __restrict__ ctx) {
  const int idx = blockIdx.x * 256 + threadIdx.x;  // < 262144
  float s = 0.f;
#pragma unroll
  for (int c = 0; c < 8; ++c) s += part[(size_t)c * 262144 + idx];
  ctx[idx] = s;
}

// ---------------------------------------------------------------------------
// K4: content[n,e,m] = sum_d ctx[n,d,e]*q[n,d,m]. grid (64 mt, 64 n)
// ---------------------------------------------------------------------------
__global__ __launch_bounds__(256) void k_content(const float* __restrict__ ctx, const bf16* __restrict__ q,
                                                 bf16* __restrict__ content) {
  const int m0 = blockIdx.x * 64, n = blockIdx.y;
  const int tx = threadIdx.x, ty = threadIdx.y;
  const int tid = ty * 16 + tx;
  __shared__ float Cs[64][65];  // Cs[d][e]
  __shared__ float Qs[64][65];  // Qs[d][j]
  const float* cn = ctx + (size_t)n * 4096;
  const bf16* qn = q + (size_t)n * DKC * MM;
#pragma unroll
  for (int l = 0; l < 16; ++l) {
    int e = tid + l * 256;
    int d = e >> 6, j = e & 63;
    Cs[d][j] = cn[e];
    Qs[d][j] = b2f(qn[(size_t)d * MM + m0 + j]);
  }
  __syncthreads();
  float acc[4][4] = {};
#pragma unroll 8
  for (int d = 0; d < 64; ++d) {
    float a[4], bbv[4];
#pragma unroll
    for (int u = 0; u < 4; ++u) a[u] = Cs[d][ty * 4 + u];
#pragma unroll
    for (int u = 0; u < 4; ++u) bbv[u] = Qs[d][tx * 4 + u];
#pragma unroll
    for (int u = 0; u < 4; ++u)
#pragma unroll
      for (int w2 = 0; w2 < 4; ++w2) acc[u][w2] += a[u] * bbv[w2];
  }
#pragma unroll
  for (int u = 0; u < 4; ++u)
#pragma unroll
    for (int w2 = 0; w2 < 4; ++w2)
      content[(size_t)n * DKC * MM + (size_t)(ty * 4 + u) * MM + m0 + tx * 4 + w2] = f2b(acc[u][w2]);
}

// ---------------------------------------------------------------------------
// K5: fused rel-row path per (n, y):  LDS phase-overlay, 49.6 KB total
//   Ss[i][x] = sum_d q[n,d,x,y]*rel_rows[i-x+63,d]
//   Yh[n,e,x,y] = sum_i v[n,e,i,y]*Ss[i][x]
// grid (64 y, 64 n), block (16,16)
// ---------------------------------------------------------------------------
__global__ __launch_bounds__(256) void k_relrow(const bf16* __restrict__ q, const bf16* __restrict__ v,
                                                const float* __restrict__ relr, bf16* __restrict__ yh) {
  const int yy = blockIdx.x, n = blockIdx.y;
  const int tx = threadIdx.x, ty = threadIdx.y;
  const int tid = ty * 16 + tx;
  __shared__ float RV[RRN * 65];  // phase1: Rr[r][d] ; phase2: Vs[e][i]
  __shared__ float QS[64 * 65];   // phase1: Qs[d][x] ; phase2: Ss[i][x]
  const size_t nb = (size_t)n * DKC * MM;
  // prefetch phase-2 (v) data into registers
  bf16 vreg[16];
#pragma unroll
  for (int l = 0; l < 16; ++l) {
    int e = tid + l * 256;
    vreg[l] = v[nb + (size_t)(e >> 6) * MM + (e & 63) * 64 + yy];
  }
  for (int e = tid; e < RRN * 64; e += 256) RV[(e >> 6) * 65 + (e & 63)] = relr[e];
#pragma unroll
  for (int l = 0; l < 16; ++l) {
    int e = tid + l * 256;
    QS[(e >> 6) * 65 + (e & 63)] = b2f(q[nb + (size_t)(e >> 6) * MM + (e & 63) * 64 + yy]);
  }
  __syncthreads();
  float acc[4][4] = {};
#pragma unroll 8
  for (int d = 0; d < 64; ++d) {
    float qv[4];
#pragma unroll
    for (int w2 = 0; w2 < 4; ++w2) qv[w2] = QS[d * 65 + tx * 4 + w2];
#pragma unroll
    for (int u = 0; u < 4; ++u) {
      const int i = ty * 4 + u;
#pragma unroll
      for (int w2 = 0; w2 < 4; ++w2) acc[u][w2] += qv[w2] * RV[(i - (tx * 4 + w2) + 63) * 65 + d];
    }
  }
  __syncthreads();
  // overlay: Ss -> QS, Vs -> RV
#pragma unroll
  for (int u = 0; u < 4; ++u)
#pragma unroll
    for (int w2 = 0; w2 < 4; ++w2) QS[(ty * 4 + u) * 65 + tx * 4 + w2] = acc[u][w2];
#pragma unroll
  for (int l = 0; l < 16; ++l) {
    int e = tid + l * 256;
    RV[(e >> 6) * 65 + (e & 63)] = b2f(vreg[l]);
  }
  __syncthreads();
  float acc2[4][4] = {};
#pragma unroll 8
  for (int i = 0; i < 64; ++i) {
    float sv[4], vv[4];
#pragma unroll
    for (int w2 = 0; w2 < 4; ++w2) sv[w2] = QS[i * 65 + tx * 4 + w2];
#pragma unroll
    for (int u = 0; u < 4; ++u) vv[u] = RV[(ty * 4 + u) * 65 + i];
#pragma unroll
    for (int u = 0; u < 4; ++u)
#pragma unroll
      for (int w2 = 0; w2 < 4; ++w2) acc2[u][w2] += vv[u] * sv[w2];
  }
#pragma unroll
  for (int u = 0; u < 4; ++u)
#pragma unroll
    for (int w2 = 0; w2 < 4; ++w2)
      yh[nb + (size_t)(ty * 4 + u) * MM + (tx * 4 + w2) * 64 + yy] = f2b(acc2[u][w2]);
}

// ---------------------------------------------------------------------------
// K6a: BN partial stats per (e, n-group of 8). grid (64, 8), block 256
// ---------------------------------------------------------------------------
__global__ __launch_bounds__(256) void k_bnpart(const bf16* __restrict__ yh, float* __restrict__ ps,
                                                float* __restrict__ ps2) {
  const int e = blockIdx.x, g = blockIdx.y;
  const int t = threadIdx.x;
  float s = 0.f, s2 = 0.f;
  for (int nn = g * 8; nn < g * 8 + 8; ++nn) {
    const bf16* p = yh + (size_t)nn * DKC * MM + (size_t)e * MM;
    for (int i = t; i < MM; i += 256) { float x = b2f(p[i]); s += x; s2 += x * x; }
  }
#pragma unroll
  for (int off = 32; off; off >>= 1) { s += __shfl_down(s, off); s2 += __shfl_down(s2, off); }
  __shared__ float r1[4], r2[4];
  if ((t & 63) == 0) { r1[t >> 6] = s; r2[t >> 6] = s2; }
  __syncthreads();
  if (t == 0) {
    ps[e * 8 + g] = r1[0] + r1[1] + r1[2] + r1[3];
    ps2[e * 8 + g] = r2[0] + r2[1] + r2[2] + r2[3];
  }
}

// K6b: finalize BN stats. grid 1, block 64
__global__ __launch_bounds__(64) void k_bnfin(const float* __restrict__ ps, const float* __restrict__ ps2,
                                              float* __restrict__ mu, float* __restrict__ rs) {
  const int e = threadIdx.x;
  float S = 0.f, S2 = 0.f;
#pragma unroll
  for (int g = 0; g < 8; ++g) { S += ps[e * 8 + g]; S2 += ps2[e * 8 + g]; }
  const float invN = 1.0f / (NH * (float)MM);
  float m = S * invN;
  float var = S2 * invN - m * m;
  mu[e] = m;
  rs[e] = 1.0f / sqrtf(var + 1e-5f);
}

// ---------------------------------------------------------------------------
// K7: fused rel-col path per (n, x):  LDS phase-overlay
//   Ss[i][y] = sum_d q[n,d,x,y]*rel_cols[i-y+63,d]
//   out[n,e,x,y] += sum_i BN(Yh[n,e,x,i])*Ss[i][y]   (accumulates into content)
// grid (64 x, 64 n), block (16,16)
// ---------------------------------------------------------------------------
__global__ __launch_bounds__(256) void k_relcol(const bf16* __restrict__ q, const bf16* __restrict__ yh,
                                                const float* __restrict__ relc, const float* __restrict__ mu,
                                                const float* __restrict__ rs, const float* __restrict__ gamma,
                                                const float* __restrict__ beta, bf16* __restrict__ outc) {
  const int xx = blockIdx.x, n = blockIdx.y;
  const int tx = threadIdx.x, ty = threadIdx.y;
  const int tid = ty * 16 + tx;
  __shared__ float RV[RRN * 65];  // phase1: Rc[r][d] ; phase2: Ys[e][i]
  __shared__ float QS[64 * 65];   // phase1: Qs[d][y] ; phase2: Ss[i][y]
  const size_t nb = (size_t)n * DKC * MM;
  // prefetch phase-2 (yh) data into registers
  bf16 yreg[16];
#pragma unroll
  for (int l = 0; l < 16; ++l) {
    int e = tid + l * 256;
    yreg[l] = yh[nb + (size_t)(e >> 6) * MM + xx * 64 + (e & 63)];
  }
  for (int e = tid; e < RRN * 64; e += 256) RV[(e >> 6) * 65 + (e & 63)] = relc[e];
#pragma unroll
  for (int l = 0; l < 16; ++l) {
    int e = tid + l * 256;
    QS[(e >> 6) * 65 + (e & 63)] = b2f(q[nb + (size_t)(e >> 6) * MM + xx * 64 + (e & 63)]);
  }
  __syncthreads();
  float acc[4][4] = {};
#pragma unroll 8
  for (int d = 0; d < 64; ++d) {
    float qv[4];
#pragma unroll
    for (int w2 = 0; w2 < 4; ++w2) qv[w2] = QS[d * 65 + tx * 4 + w2];
#pragma unroll
    for (int u = 0; u < 4; ++u) {
      const int i = ty * 4 + u;
#pragma unroll
      for (int w2 = 0; w2 < 4; ++w2) acc[u][w2] += qv[w2] * RV[(i - (tx * 4 + w2) + 63) * 65 + d];
    }
  }
  __syncthreads();
  // overlay: Ss -> QS, Ys(BN applied) -> RV
#pragma unroll
  for (int u = 0; u < 4; ++u)
#pragma unroll
    for (int w2 = 0; w2 < 4; ++w2) QS[(ty * 4 + u) * 65 + tx * 4 + w2] = acc[u][w2];
#pragma unroll
  for (int l = 0; l < 16; ++l) {
    int e = tid + l * 256;
    int ee = e >> 6;
    RV[ee * 65 + (e & 63)] = (b2f(yreg[l]) - mu[ee]) * rs[ee] * gamma[ee] + beta[ee];
  }
  __syncthreads();
  float acc2[4][4] = {};
#pragma unroll 8
  for (int i = 0; i < 64; ++i) {
    float sv[4], yv[4];
#pragma unroll
    for (int w2 = 0; w2 < 4; ++w2) sv[w2] = QS[i * 65 + tx * 4 + w2];
#pragma unroll
    for (int u = 0; u < 4; ++u) yv[u] = RV[(ty * 4 + u) * 65 + i];
#pragma unroll
    for (int u = 0; u < 4; ++u)
#pragma unroll
      for (int w2 = 0; w2 < 4; ++w2) acc2[u][w2] += yv[u] * sv[w2];
  }
#pragma unroll
  for (int u = 0; u < 4; ++u)
#pragma unroll
    for (int w2 = 0; w2 < 4; ++w2) {
      size_t a = nb + (size_t)(ty * 4 + u) * MM + xx * 64 + tx * 4 + w2;
      outc[a] = f2b(b2f(outc[a]) + acc2[u][w2]);
    }
}

// ---------------------------------------------------------------------------
// K8: final = Wout(256x512) @ combined_b(512x4096) + bias. grid (64 mt, 4 ot, 8 b)
// ---------------------------------------------------------------------------
__global__ __launch_bounds__(256) void k_final(const bf16* __restrict__ src, const float* __restrict__ wout,
                                               const float* __restrict__ bout, float* __restrict__ dout) {
  const int b = blockIdx.z;
  const int o0 = blockIdx.y * 64;
  const int m0 = blockIdx.x * 64;
  const int tx = threadIdx.x, ty = threadIdx.y;
  const int tid = ty * 16 + tx;
  __shared__ float As[16][65];
  __shared__ float Bs[16][65];
  float acc[4][4] = {};
  const bf16* sb = src + (size_t)b * 512 * MM;
  for (int k0 = 0; k0 < 512; k0 += 16) {
#pragma unroll
    for (int l = 0; l < 4; ++l) {
      int e = tid + l * 256;
      int i = e >> 4, kj = e & 15;
      As[kj][i] = wout[(size_t)(o0 + i) * 512 + k0 + kj];
      int kj2 = e >> 6, j = e & 63;
      Bs[kj2][j] = b2f(sb[(size_t)(k0 + kj2) * MM + m0 + j]);
    }
    __syncthreads();
#pragma unroll
    for (int kj = 0; kj < 16; ++kj) {
      float a[4], bbv[4];
#pragma unroll
      for (int u = 0; u < 4; ++u) a[u] = As[kj][ty * 4 + u];
#pragma unroll
      for (int u = 0; u < 4; ++u) bbv[u] = Bs[kj][tx * 4 + u];
#pragma unroll
      for (int u = 0; u < 4; ++u)
#pragma unroll
        for (int w2 = 0; w2 < 4; ++w2) acc[u][w2] += a[u] * bbv[w2];
    }
    __syncthreads();
  }
#pragma unroll
  for (int u = 0; u < 4; ++u) {
    const float bias = bout[o0 + ty * 4 + u];
#pragma unroll
    for (int w2 = 0; w2 < 4; ++w2)
      dout[((size_t)b * 256 + o0 + ty * 4 + u) * MM + m0 + tx * 4 + w2] = acc[u][w2] + bias;
  }
}

// ---------------------------------------------------------------------------
extern "C" void kernel_launch(void* const* d_in, const int* in_sizes, int n_in,
                              void* d_out, int out_size, void* d_ws, size_t ws_size,
                              hipStream_t stream) {
  const float* img = (const float*)d_in[0];
  const float* w_qkv = (const float*)d_in[1];
  const float* w_out = (const float*)d_in[2];
  const float* b_out = (const float*)d_in[3];
  const float* rel_rows = (const float*)d_in[4];
  const float* rel_cols = (const float*)d_in[5];
  const float* gamma = (const float*)d_in[6];
  const float* beta = (const float*)d_in[7];
  float* out = (float*)d_out;

  const size_t SZ = (size_t)NH * DKC * MM;  // 16,777,216 elements
  bf16* q = (bf16*)d_ws;          // SZ bf16
  bf16* kbuf = q + SZ;            // SZ bf16: k, later reused as yh
  bf16* vbuf = kbuf + SZ;         // SZ bf16: v, later reused as content
  bf16* imgT = vbuf + SZ;         // 8,388,608 bf16 (16.8 MB), dead after k_qkv
  // union region overlaid on imgT (alive only after k_qkv):
  float* ctxp = (float*)imgT;     // 2,097,152 f32
  float* ctx = ctxp + 2097152;    // 262,144 f32
  float* ps = ctx + 262144;       // 512
  float* ps2 = ps + 512;          // 512
  float* mu = ps2 + 512;          // 64
  float* rs = mu + 64;            // 64  (total 9.44 MB < 16.8 MB union)
  bf16* wb = imgT + 8388608;      // 393,216 bf16
  // total ~118.3 MB

  k_cvt_w<<<1536, 256, 0, stream>>>(w_qkv, wb);
  k_timg<<<dim3(64, 4, 8), 256, 0, stream>>>(img, imgT);
  k_qkv<<<dim3(32, 12, 8), 256, 0, stream>>>(wb, imgT, q, kbuf, vbuf);
  k_softmax<<<4096, 256, 0, stream>>>(kbuf);
  k_ctx_part<<<dim3(8, 64), dim3(16, 16), 0, stream>>>(kbuf, vbuf, ctxp);
  k_ctx_red<<<1024, 256, 0, stream>>>(ctxp, ctx);
  // k dead -> kbuf becomes yh
  k_relrow<<<dim3(64, 64), dim3(16, 16), 0, stream>>>(q, vbuf, rel_rows, kbuf);
  k_bnpart<<<dim3(64, 8), 256, 0, stream>>>(kbuf, ps, ps2);
  k_bnfin<<<1, 64, 0, stream>>>(ps, ps2, mu, rs);
  // v dead -> vbuf becomes content
  k_content<<<dim3(64, 64), dim3(16, 16), 0, stream>>>(ctx, q, vbuf);
  k_relcol<<<dim3(64, 64), dim3(16, 16), 0, stream>>>(q, kbuf, rel_cols, mu, rs, gamma, beta, vbuf);
  k_final<<<dim3(64, 4, 8), dim3(16, 16), 0, stream>>>(vbuf, w_out, b_out, out);
}

// Round 4
// 630.052 us; speedup vs baseline: 1.9458x; 1.2725x over previous
//
#include <hip/hip_runtime.h>
#include <hip/hip_bf16.h>
#include <math.h>

// Problem constants
#define NH   64     // b*H heads
#define DKC  64     // dim per head
#define MM   4096   // x*y
#define CC   256    // img channels
#define RRN  127    // 2L-1

typedef __hip_bfloat16 bf16;
__device__ __forceinline__ float b2f(bf16 x) { return __bfloat162float(x); }
__device__ __forceinline__ bf16 f2b(float x) { return __float2bfloat16(x); }

typedef short bf16x8 __attribute__((ext_vector_type(8)));
typedef float f32x4 __attribute__((ext_vector_type(4)));
typedef unsigned short u16;
typedef u16 u16x4 __attribute__((ext_vector_type(4)));

#define AS1 __attribute__((address_space(1)))
#define AS3 __attribute__((address_space(3)))
#define GLOAD16(gp, lp) __builtin_amdgcn_global_load_lds((const AS1 void*)(gp), (AS3 void*)(lp), 16, 0, 0)

// ---------------------------------------------------------------------------
// K0a: convert w_qkv fp32 -> bf16
// ---------------------------------------------------------------------------
__global__ __launch_bounds__(256) void k_cvt_w(const float* __restrict__ w, bf16* __restrict__ wb) {
  const int i = blockIdx.x * 256 + threadIdx.x;
  wb[i] = f2b(w[i]);
}

// ---------------------------------------------------------------------------
// K0b: img fp32 [8][256][4096] -> bf16 imgT [8][4096][256]
// ---------------------------------------------------------------------------
__global__ __launch_bounds__(256) void k_timg(const float* __restrict__ img, bf16* __restrict__ imgT) {
  const int b = blockIdx.z, c0 = blockIdx.y * 64, m0 = blockIdx.x * 64;
  const int tid = threadIdx.x;
  __shared__ bf16 T[64][65];
  const float* ib = img + ((size_t)b * CC + c0) * MM + m0;
#pragma unroll
  for (int l = 0; l < 16; ++l) {
    int e = tid + l * 256;
    int cc = e >> 6, mm = e & 63;
    T[cc][mm] = f2b(ib[(size_t)cc * MM + mm]);
  }
  __syncthreads();
  bf16* ob = imgT + ((size_t)b * MM + m0) * CC + c0;
#pragma unroll
  for (int l = 0; l < 16; ++l) {
    int e = tid + l * 256;
    int mm = e >> 6, cc = e & 63;
    ob[(size_t)mm * CC + cc] = T[cc][mm];
  }
}

// ---------------------------------------------------------------------------
// K1: MFMA qkv GEMM (128x128 tile, BK=64, 4 waves)
// ---------------------------------------------------------------------------
__global__ __launch_bounds__(256) void k_qkv(const bf16* __restrict__ wb, const bf16* __restrict__ imgT,
                                             bf16* __restrict__ q, bf16* __restrict__ kk, bf16* __restrict__ v) {
  const int bI = blockIdx.z;
  const int o0 = blockIdx.y * 128;
  const int m0 = blockIdx.x * 128;
  const int tid = threadIdx.x;
  const int lane = tid & 63, wid = tid >> 6;
  const int fr = lane & 15;
  const int fq = lane >> 4;
  const int wm = (wid >> 1) * 64, wn = (wid & 1) * 64;

  __shared__ __align__(16) short As[128 * 64];
  __shared__ __align__(16) short Bs[128 * 64];

  const bf16* iB = imgT + (size_t)bI * MM * CC;

  f32x4 acc[4][4];
#pragma unroll
  for (int mi = 0; mi < 4; ++mi)
#pragma unroll
    for (int ni = 0; ni < 4; ++ni) acc[mi][ni] = (f32x4){0.f, 0.f, 0.f, 0.f};

  const int srow = lane >> 3;
  const int skc = (lane & 7) * 8;

  for (int kt = 0; kt < 4; ++kt) {
    const int k0 = kt * 64;
#pragma unroll
    for (int cc = 0; cc < 4; ++cc) {
      const int c = wid * 4 + cc;
      const int r = c * 8 + srow;
      GLOAD16(wb + (size_t)(o0 + r) * CC + k0 + skc, &As[c * 512]);
      GLOAD16(iB + (size_t)(m0 + r) * CC + k0 + skc, &Bs[c * 512]);
    }
    __syncthreads();
    bf16x8 af[4][2], bfr[4][2];
#pragma unroll
    for (int mi = 0; mi < 4; ++mi)
#pragma unroll
      for (int kkk = 0; kkk < 2; ++kkk)
        af[mi][kkk] = *(const bf16x8*)&As[(wm + mi * 16 + fr) * 64 + kkk * 32 + fq * 8];
#pragma unroll
    for (int ni = 0; ni < 4; ++ni)
#pragma unroll
      for (int kkk = 0; kkk < 2; ++kkk)
        bfr[ni][kkk] = *(const bf16x8*)&Bs[(wn + ni * 16 + fr) * 64 + kkk * 32 + fq * 8];
#pragma unroll
    for (int mi = 0; mi < 4; ++mi)
#pragma unroll
      for (int ni = 0; ni < 4; ++ni)
#pragma unroll
        for (int kkk = 0; kkk < 2; ++kkk)
          acc[mi][ni] = __builtin_amdgcn_mfma_f32_16x16x32_bf16(af[mi][kkk], bfr[ni][kkk], acc[mi][ni], 0, 0, 0);
    __syncthreads();
  }

#pragma unroll
  for (int mi = 0; mi < 4; ++mi) {
#pragma unroll
    for (int ni = 0; ni < 4; ++ni) {
      const int mcol = m0 + wn + ni * 16 + fr;
#pragma unroll
      for (int r = 0; r < 4; ++r) {
        int oo = o0 + wm + mi * 16 + fq * 4 + r;
        bf16* dst;
        if (oo < 512) { dst = q; }
        else if (oo < 1024) { dst = kk; oo -= 512; }
        else { dst = v; oo -= 1024; }
        dst[((size_t)bI * 512 + oo) * MM + mcol] = f2b(acc[mi][ni][r]);
      }
    }
  }
}

// ---------------------------------------------------------------------------
// K2: in-place softmax over m=4096 per (n,d) row
// ---------------------------------------------------------------------------
__global__ __launch_bounds__(256) void k_softmax(bf16* __restrict__ kk) {
  const size_t row = blockIdx.x;
  bf16* p = kk + row * (size_t)MM;
  const int t = threadIdx.x;
  __shared__ float sred[4];
  float mx = -1e30f;
  for (int i = t; i < MM; i += 256) mx = fmaxf(mx, b2f(p[i]));
#pragma unroll
  for (int off = 32; off; off >>= 1) mx = fmaxf(mx, __shfl_down(mx, off));
  if ((t & 63) == 0) sred[t >> 6] = mx;
  __syncthreads();
  mx = fmaxf(fmaxf(sred[0], sred[1]), fmaxf(sred[2], sred[3]));
  __syncthreads();
  float s = 0.f;
  for (int i = t; i < MM; i += 256) { float e = expf(b2f(p[i]) - mx); p[i] = f2b(e); s += e; }
#pragma unroll
  for (int off = 32; off; off >>= 1) s += __shfl_down(s, off);
  if ((t & 63) == 0) sred[t >> 6] = s;
  __syncthreads();
  s = sred[0] + sred[1] + sred[2] + sred[3];
  const float inv = 1.0f / s;
  for (int i = t; i < MM; i += 256) p[i] = f2b(b2f(p[i]) * inv);
}

// ---------------------------------------------------------------------------
// K3a: partial context[n,d,e] = sum_m k[n,d,m]*v[n,e,m]
// ---------------------------------------------------------------------------
__global__ __launch_bounds__(256) void k_ctx_part(const bf16* __restrict__ kk, const bf16* __restrict__ v,
                                                  float* __restrict__ part) {
  const int ch = blockIdx.x, n = blockIdx.y;
  const int tx = threadIdx.x, ty = threadIdx.y;
  const int tid = ty * 16 + tx;
  __shared__ float Ks[64][65];
  __shared__ float Vs[64][65];
  float acc[4][4] = {};
  const bf16* kp = kk + (size_t)n * DKC * MM;
  const bf16* vp = v + (size_t)n * DKC * MM;
  for (int m0 = ch * 512; m0 < ch * 512 + 512; m0 += 64) {
#pragma unroll
    for (int l = 0; l < 16; ++l) {
      int e = tid + l * 256;
      int d = e >> 6, j = e & 63;
      Ks[d][j] = b2f(kp[(size_t)d * MM + m0 + j]);
      Vs[d][j] = b2f(vp[(size_t)d * MM + m0 + j]);
    }
    __syncthreads();
#pragma unroll
    for (int j = 0; j < 64; ++j) {
      float a[4], bbv[4];
#pragma unroll
      for (int u = 0; u < 4; ++u) a[u] = Ks[ty * 4 + u][j];
#pragma unroll
      for (int u = 0; u < 4; ++u) bbv[u] = Vs[tx * 4 + u][j];
#pragma unroll
      for (int u = 0; u < 4; ++u)
#pragma unroll
        for (int w2 = 0; w2 < 4; ++w2) acc[u][w2] += a[u] * bbv[w2];
    }
    __syncthreads();
  }
#pragma unroll
  for (int u = 0; u < 4; ++u)
#pragma unroll
    for (int w2 = 0; w2 < 4; ++w2)
      part[((size_t)ch * NH + n) * 4096 + (ty * 4 + u) * 64 + tx * 4 + w2] = acc[u][w2];
}

// K3b: reduce 8 partials
__global__ __launch_bounds__(256) void k_ctx_red(const float* __restrict__ part, float* __restrict__ ctx) {
  const int idx = blockIdx.x * 256 + threadIdx.x;
  float s = 0.f;
#pragma unroll
  for (int c = 0; c < 8; ++c) s += part[(size_t)c * 262144 + idx];
  ctx[idx] = s;
}

// ---------------------------------------------------------------------------
// K4: content[n,e,m] = sum_d ctx[n,d,e]*q[n,d,m]
// ---------------------------------------------------------------------------
__global__ __launch_bounds__(256) void k_content(const float* __restrict__ ctx, const bf16* __restrict__ q,
                                                 bf16* __restrict__ content) {
  const int m0 = blockIdx.x * 64, n = blockIdx.y;
  const int tx = threadIdx.x, ty = threadIdx.y;
  const int tid = ty * 16 + tx;
  __shared__ float Cs[64][65];
  __shared__ float Qs[64][65];
  const float* cn = ctx + (size_t)n * 4096;
  const bf16* qn = q + (size_t)n * DKC * MM;
#pragma unroll
  for (int l = 0; l < 16; ++l) {
    int e = tid + l * 256;
    int d = e >> 6, j = e & 63;
    Cs[d][j] = cn[e];
    Qs[d][j] = b2f(qn[(size_t)d * MM + m0 + j]);
  }
  __syncthreads();
  float acc[4][4] = {};
#pragma unroll 8
  for (int d = 0; d < 64; ++d) {
    float a[4], bbv[4];
#pragma unroll
    for (int u = 0; u < 4; ++u) a[u] = Cs[d][ty * 4 + u];
#pragma unroll
    for (int u = 0; u < 4; ++u) bbv[u] = Qs[d][tx * 4 + u];
#pragma unroll
    for (int u = 0; u < 4; ++u)
#pragma unroll
      for (int w2 = 0; w2 < 4; ++w2) acc[u][w2] += a[u] * bbv[w2];
  }
#pragma unroll
  for (int u = 0; u < 4; ++u)
#pragma unroll
    for (int w2 = 0; w2 < 4; ++w2)
      content[(size_t)n * DKC * MM + (size_t)(ty * 4 + u) * MM + m0 + tx * 4 + w2] = f2b(acc[u][w2]);
}

// ---------------------------------------------------------------------------
// K5a: k_sx — rel-row stage 1, standard GEMM per (n,x):
//   Sx[n][x][i][y] = sum_d relr[i-x+63][d] * q[n,d,x*64+y]
// grid (64 x, 64 n), block (16,16). All IO coalesced; LDS conflict-free.
// ---------------------------------------------------------------------------
__global__ __launch_bounds__(256) void k_sx(const float* __restrict__ relr, const bf16* __restrict__ q,
                                            bf16* __restrict__ sx) {
  const int x = blockIdx.x, n = blockIdx.y;
  const int tx = threadIdx.x, ty = threadIdx.y;
  const int tid = ty * 16 + tx;
  __shared__ float Af[64 * 66];   // Af[d][i] = relr[i+63-x][d]
  __shared__ bf16 Qs[64 * 66];    // Qs[d][y]
  const size_t nb = (size_t)n * DKC * MM;
  for (int t = tid; t < 4096; t += 256) {
    int i = t >> 6, d = t & 63;
    Af[d * 66 + i] = relr[(i + 63 - x) * 64 + d];
  }
  for (int t = tid; t < 4096; t += 256) {
    int d = t >> 6, y = t & 63;
    Qs[d * 66 + y] = q[nb + (size_t)d * MM + x * 64 + y];
  }
  __syncthreads();
  float acc[4][4] = {};
#pragma unroll 8
  for (int d = 0; d < 64; ++d) {
    float a[4], b[4];
#pragma unroll
    for (int u = 0; u < 4; ++u) a[u] = Af[d * 66 + 4 * ty + u];
#pragma unroll
    for (int w2 = 0; w2 < 4; ++w2) b[w2] = b2f(Qs[d * 66 + 4 * tx + w2]);
#pragma unroll
    for (int u = 0; u < 4; ++u)
#pragma unroll
      for (int w2 = 0; w2 < 4; ++w2) acc[u][w2] += a[u] * b[w2];
  }
  const size_t sxbase = ((size_t)(n * 64 + x)) * 4096;
#pragma unroll
  for (int u = 0; u < 4; ++u) {
    u16x4 pk;
#pragma unroll
    for (int w2 = 0; w2 < 4; ++w2) { bf16 hb = f2b(acc[u][w2]); pk[w2] = *(u16*)&hb; }
    *(u16x4*)&sx[sxbase + (size_t)(4 * ty + u) * 64 + 4 * tx] = pk;
  }
}

// ---------------------------------------------------------------------------
// K5b: k_yh — rel-row stage 2, lane=y vectorized:
//   Yh[n,e,x,y] = sum_i v[n,e,i*64+y] * Sx[n,x,i,y]
// grid (8 xg, 4 et, 64 n), block (64,4). All loads/stores 128B-contiguous.
// ---------------------------------------------------------------------------
__global__ __launch_bounds__(256) void k_yh(const bf16* __restrict__ v, const bf16* __restrict__ sx,
                                            bf16* __restrict__ yh) {
  const int xg = blockIdx.x, et = blockIdx.y, n = blockIdx.z;
  const int y = threadIdx.x, s = threadIdx.y;
  const int eb = et * 16 + s * 4;
  const size_t nb = (size_t)n * DKC * MM;
  const bf16* vp = v + nb;
  const bf16* sp = sx + ((size_t)(n * 64 + xg * 8)) * 4096;
  float acc[4][8] = {};
#pragma unroll 4
  for (int i = 0; i < 64; ++i) {
    float vv[4], ss[8];
#pragma unroll
    for (int ee = 0; ee < 4; ++ee) vv[ee] = b2f(vp[(size_t)(eb + ee) * MM + i * 64 + y]);
#pragma unroll
    for (int xx = 0; xx < 8; ++xx) ss[xx] = b2f(sp[(size_t)(xx * 64 + i) * 64 + y]);
#pragma unroll
    for (int ee = 0; ee < 4; ++ee)
#pragma unroll
      for (int xx = 0; xx < 8; ++xx) acc[ee][xx] += vv[ee] * ss[xx];
  }
#pragma unroll
  for (int ee = 0; ee < 4; ++ee)
#pragma unroll
    for (int xx = 0; xx < 8; ++xx)
      yh[nb + (size_t)(eb + ee) * MM + (xg * 8 + xx) * 64 + y] = f2b(acc[ee][xx]);
}

// ---------------------------------------------------------------------------
// K6a: BN partial stats per (e, n-group of 8)
// ---------------------------------------------------------------------------
__global__ __launch_bounds__(256) void k_bnpart(const bf16* __restrict__ yh, float* __restrict__ ps,
                                                float* __restrict__ ps2) {
  const int e = blockIdx.x, g = blockIdx.y;
  const int t = threadIdx.x;
  float s = 0.f, s2 = 0.f;
  for (int nn = g * 8; nn < g * 8 + 8; ++nn) {
    const bf16* p = yh + (size_t)nn * DKC * MM + (size_t)e * MM;
    for (int i = t; i < MM; i += 256) { float x = b2f(p[i]); s += x; s2 += x * x; }
  }
#pragma unroll
  for (int off = 32; off; off >>= 1) { s += __shfl_down(s, off); s2 += __shfl_down(s2, off); }
  __shared__ float r1[4], r2[4];
  if ((t & 63) == 0) { r1[t >> 6] = s; r2[t >> 6] = s2; }
  __syncthreads();
  if (t == 0) {
    ps[e * 8 + g] = r1[0] + r1[1] + r1[2] + r1[3];
    ps2[e * 8 + g] = r2[0] + r2[1] + r2[2] + r2[3];
  }
}

// K6b: finalize BN stats
__global__ __launch_bounds__(64) void k_bnfin(const float* __restrict__ ps, const float* __restrict__ ps2,
                                              float* __restrict__ mu, float* __restrict__ rs) {
  const int e = threadIdx.x;
  float S = 0.f, S2 = 0.f;
#pragma unroll
  for (int g = 0; g < 8; ++g) { S += ps[e * 8 + g]; S2 += ps2[e * 8 + g]; }
  const float invN = 1.0f / (NH * (float)MM);
  float m = S * invN;
  float var = S2 * invN - m * m;
  mu[e] = m;
  rs[e] = 1.0f / sqrtf(var + 1e-5f);
}

// ---------------------------------------------------------------------------
// K7: k_relcol2 — fused rel-col per (n,x) using the shift identity:
//   Sc'[j][y] = sum_d relc[j][d]*q[n,d,x*64+y]   (plain 127x64x64 GEMM in LDS)
//   out[e,y] += sum_i BN(yh[n,e,x*64+i]) * Sc'[i-y+63][y]
// grid (64 x, 64 n), block (16,16). LDS 58.6 KB, padded strides (bank-clean).
// ---------------------------------------------------------------------------
__global__ __launch_bounds__(256) void k_relcol2(const bf16* __restrict__ q, const bf16* __restrict__ yh,
                                                 const float* __restrict__ relc, const float* __restrict__ mu,
                                                 const float* __restrict__ rs, const float* __restrict__ gamma,
                                                 const float* __restrict__ beta, bf16* __restrict__ outc) {
  const int xx = blockIdx.x, n = blockIdx.y;
  const int tx = threadIdx.x, ty = threadIdx.y;
  const int tid = ty * 16 + tx;
  __shared__ __align__(16) unsigned char smem[16640 + 8448 + 33528];
  bf16* Ab = (bf16*)smem;                    // [64][130] A^T: Ab[d][j]=relc[j][d]
  bf16* Qs = (bf16*)(smem + 16640);          // [64][66]
  float* Sc = (float*)(smem + 16640 + 8448); // [127][66]
  float* Ys = (float*)smem;                  // overlay on Ab after stage 1: [64][65]
  const size_t nb = (size_t)n * DKC * MM;

  for (int t = tid; t < RRN * 64; t += 256) {
    int j = t >> 6, d = t & 63;
    Ab[d * 130 + j] = f2b(relc[t]);
  }
  for (int t = tid; t < 4096; t += 256) {
    int d = t >> 6, y = t & 63;
    Qs[d * 66 + y] = q[nb + (size_t)d * MM + xx * 64 + y];
  }
  __syncthreads();

  // stage 1: Sc'[j][y], j = ty + 16u
  float acc1[8][4] = {};
#pragma unroll 8
  for (int d = 0; d < 64; ++d) {
    float a[8], b[4];
#pragma unroll
    for (int u = 0; u < 8; ++u) a[u] = b2f(Ab[d * 130 + ty + 16 * u]);
#pragma unroll
    for (int w2 = 0; w2 < 4; ++w2) b[w2] = b2f(Qs[d * 66 + 4 * tx + w2]);
#pragma unroll
    for (int u = 0; u < 8; ++u)
#pragma unroll
      for (int w2 = 0; w2 < 4; ++w2) acc1[u][w2] += a[u] * b[w2];
  }
#pragma unroll
  for (int u = 0; u < 8; ++u) {
    int j = ty + 16 * u;
    if (j < RRN) {
#pragma unroll
      for (int w2 = 0; w2 < 4; ++w2) Sc[j * 66 + 4 * tx + w2] = acc1[u][w2];
    }
  }
  __syncthreads();

  // stage Ys = BN(yh) into overlay
  for (int t = tid; t < 4096; t += 256) {
    int e = t >> 6, i = t & 63;
    Ys[e * 65 + i] = (b2f(yh[nb + (size_t)e * MM + xx * 64 + i]) - mu[e]) * rs[e] * gamma[e] + beta[e];
  }
  __syncthreads();

  // stage 2: out[e][y] += sum_i Ys[e][i] * Sc[i-y+63][y]
  float acc2[4][4] = {};
#pragma unroll 8
  for (int i = 0; i < 64; ++i) {
    float yv[4], sv[4];
#pragma unroll
    for (int u = 0; u < 4; ++u) yv[u] = Ys[(4 * ty + u) * 65 + i];
#pragma unroll
    for (int w2 = 0; w2 < 4; ++w2) {
      int y = 4 * tx + w2;
      sv[w2] = Sc[(i - y + 63) * 66 + y];
    }
#pragma unroll
    for (int u = 0; u < 4; ++u)
#pragma unroll
      for (int w2 = 0; w2 < 4; ++w2) acc2[u][w2] += yv[u] * sv[w2];
  }
#pragma unroll
  for (int u = 0; u < 4; ++u)
#pragma unroll
    for (int w2 = 0; w2 < 4; ++w2) {
      size_t a = nb + (size_t)(4 * ty + u) * MM + xx * 64 + 4 * tx + w2;
      outc[a] = f2b(b2f(outc[a]) + acc2[u][w2]);
    }
}

// ---------------------------------------------------------------------------
// K8: final = Wout(256x512) @ combined_b(512x4096) + bias
// ---------------------------------------------------------------------------
__global__ __launch_bounds__(256) void k_final(const bf16* __restrict__ src, const float* __restrict__ wout,
                                               const float* __restrict__ bout, float* __restrict__ dout) {
  const int b = blockIdx.z;
  const int o0 = blockIdx.y * 64;
  const int m0 = blockIdx.x * 64;
  const int tx = threadIdx.x, ty = threadIdx.y;
  const int tid = ty * 16 + tx;
  __shared__ float As[16][65];
  __shared__ float Bs[16][65];
  float acc[4][4] = {};
  const bf16* sb = src + (size_t)b * 512 * MM;
  for (int k0 = 0; k0 < 512; k0 += 16) {
#pragma unroll
    for (int l = 0; l < 4; ++l) {
      int e = tid + l * 256;
      int i = e >> 4, kj = e & 15;
      As[kj][i] = wout[(size_t)(o0 + i) * 512 + k0 + kj];
      int kj2 = e >> 6, j = e & 63;
      Bs[kj2][j] = b2f(sb[(size_t)(k0 + kj2) * MM + m0 + j]);
    }
    __syncthreads();
#pragma unroll
    for (int kj = 0; kj < 16; ++kj) {
      float a[4], bbv[4];
#pragma unroll
      for (int u = 0; u < 4; ++u) a[u] = As[kj][ty * 4 + u];
#pragma unroll
      for (int u = 0; u < 4; ++u) bbv[u] = Bs[kj][tx * 4 + u];
#pragma unroll
      for (int u = 0; u < 4; ++u)
#pragma unroll
        for (int w2 = 0; w2 < 4; ++w2) acc[u][w2] += a[u] * bbv[w2];
    }
    __syncthreads();
  }
#pragma unroll
  for (int u = 0; u < 4; ++u) {
    const float bias = bout[o0 + ty * 4 + u];
#pragma unroll
    for (int w2 = 0; w2 < 4; ++w2)
      dout[((size_t)b * 256 + o0 + ty * 4 + u) * MM + m0 + tx * 4 + w2] = acc[u][w2] + bias;
  }
}

// ---------------------------------------------------------------------------
extern "C" void kernel_launch(void* const* d_in, const int* in_sizes, int n_in,
                              void* d_out, int out_size, void* d_ws, size_t ws_size,
                              hipStream_t stream) {
  const float* img = (const float*)d_in[0];
  const float* w_qkv = (const float*)d_in[1];
  const float* w_out = (const float*)d_in[2];
  const float* b_out = (const float*)d_in[3];
  const float* rel_rows = (const float*)d_in[4];
  const float* rel_cols = (const float*)d_in[5];
  const float* gamma = (const float*)d_in[6];
  const float* beta = (const float*)d_in[7];
  float* out = (float*)d_out;

  const size_t SZ = (size_t)NH * DKC * MM;  // 16,777,216 elements
  bf16* q = (bf16*)d_ws;          // SZ bf16
  bf16* kbuf = q + SZ;            // SZ bf16: k, later reused as yh
  bf16* vbuf = kbuf + SZ;         // SZ bf16: v, later reused as content
  bf16* imgT = vbuf + SZ;         // 8,388,608 bf16, dead after k_qkv
  // union region overlaid on imgT (alive only after k_qkv):
  float* ctxp = (float*)imgT;     // 2,097,152 f32
  float* ctx = ctxp + 2097152;    // 262,144 f32
  float* ps = ctx + 262144;       // 512
  float* ps2 = ps + 512;          // 512
  float* mu = ps2 + 512;          // 64
  float* rs = mu + 64;            // 64
  bf16* wb = imgT + 8388608;      // 393,216 bf16
  bf16* sxbuf = wb + 393216;      // SZ bf16 (33.5 MB)
  // total ~151.8 MB

  k_cvt_w<<<1536, 256, 0, stream>>>(w_qkv, wb);
  k_timg<<<dim3(64, 4, 8), 256, 0, stream>>>(img, imgT);
  k_qkv<<<dim3(32, 12, 8), 256, 0, stream>>>(wb, imgT, q, kbuf, vbuf);
  k_softmax<<<4096, 256, 0, stream>>>(kbuf);
  k_ctx_part<<<dim3(8, 64), dim3(16, 16), 0, stream>>>(kbuf, vbuf, ctxp);
  k_ctx_red<<<1024, 256, 0, stream>>>(ctxp, ctx);
  // rel-row path (kbuf dead -> becomes yh)
  k_sx<<<dim3(64, 64), dim3(16, 16), 0, stream>>>(rel_rows, q, sxbuf);
  k_yh<<<dim3(8, 4, 64), dim3(64, 4), 0, stream>>>(vbuf, sxbuf, kbuf);
  k_bnpart<<<dim3(64, 8), 256, 0, stream>>>(kbuf, ps, ps2);
  k_bnfin<<<1, 64, 0, stream>>>(ps, ps2, mu, rs);
  // v dead -> vbuf becomes content
  k_content<<<dim3(64, 64), dim3(16, 16), 0, stream>>>(ctx, q, vbuf);
  k_relcol2<<<dim3(64, 64), dim3(16, 16), 0, stream>>>(q, kbuf, rel_cols, mu, rs, gamma, beta, vbuf);
  k_final<<<dim3(64, 4, 8), dim3(16, 16), 0, stream>>>(vbuf, w_out, b_out, out);
}

// Round 5
// 487.345 us; speedup vs baseline: 2.5156x; 1.2928x over previous
//
#include <hip/hip_runtime.h>
#include <hip/hip_bf16.h>
#include <math.h>

// Problem constants
#define NH   64     // b*H heads
#define DKC  64     // dim per head
#define MM   4096   // x*y
#define CC   256    // img channels
#define RRN  127    // 2L-1

typedef __hip_bfloat16 bf16;
__device__ __forceinline__ float b2f(bf16 x) { return __bfloat162float(x); }
__device__ __forceinline__ bf16 f2b(float x) { return __float2bfloat16(x); }
__device__ __forceinline__ unsigned short bbits(float x) { bf16 h = f2b(x); return *(unsigned short*)&h; }
__device__ __forceinline__ float fbits(unsigned short u) { bf16 h = *(bf16*)&u; return b2f(h); }

typedef short bf16x8 __attribute__((ext_vector_type(8)));
typedef float f32x4 __attribute__((ext_vector_type(4)));
typedef unsigned short u16;
typedef u16 u16x4 __attribute__((ext_vector_type(4)));

#define AS1 __attribute__((address_space(1)))
#define AS3 __attribute__((address_space(3)))
#define GLOAD16(gp, lp) __builtin_amdgcn_global_load_lds((const AS1 void*)(gp), (AS3 void*)(lp), 16, 0, 0)

// ---------------------------------------------------------------------------
// K0a: convert w_qkv fp32 -> bf16 (393216 elems)
// ---------------------------------------------------------------------------
__global__ __launch_bounds__(256) void k_cvt_w(const float* __restrict__ w, bf16* __restrict__ wb) {
  const int i = blockIdx.x * 256 + threadIdx.x;
  wb[i] = f2b(w[i]);
}

// K0c: convert w_out fp32 -> bf16 (131072 elems)
__global__ __launch_bounds__(256) void k_cvt_w2(const float* __restrict__ w, bf16* __restrict__ wb) {
  const int i = blockIdx.x * 256 + threadIdx.x;
  wb[i] = f2b(w[i]);
}

// ---------------------------------------------------------------------------
// K0b: img fp32 [8][256][4096] -> bf16 imgT [8][4096][256]
// ---------------------------------------------------------------------------
__global__ __launch_bounds__(256) void k_timg(const float* __restrict__ img, bf16* __restrict__ imgT) {
  const int b = blockIdx.z, c0 = blockIdx.y * 64, m0 = blockIdx.x * 64;
  const int tid = threadIdx.x;
  __shared__ bf16 T[64][65];
  const float* ib = img + ((size_t)b * CC + c0) * MM + m0;
#pragma unroll
  for (int l = 0; l < 16; ++l) {
    int e = tid + l * 256;
    int cc = e >> 6, mm = e & 63;
    T[cc][mm] = f2b(ib[(size_t)cc * MM + mm]);
  }
  __syncthreads();
  bf16* ob = imgT + ((size_t)b * MM + m0) * CC + c0;
#pragma unroll
  for (int l = 0; l < 16; ++l) {
    int e = tid + l * 256;
    int mm = e >> 6, cc = e & 63;
    ob[(size_t)mm * CC + cc] = T[cc][mm];
  }
}

// ---------------------------------------------------------------------------
// K1: MFMA qkv GEMM (128x128 tile, BK=64, 4 waves)
// ---------------------------------------------------------------------------
__global__ __launch_bounds__(256) void k_qkv(const bf16* __restrict__ wb, const bf16* __restrict__ imgT,
                                             bf16* __restrict__ q, bf16* __restrict__ kk, bf16* __restrict__ v) {
  const int bI = blockIdx.z;
  const int o0 = blockIdx.y * 128;
  const int m0 = blockIdx.x * 128;
  const int tid = threadIdx.x;
  const int lane = tid & 63, wid = tid >> 6;
  const int fr = lane & 15;
  const int fq = lane >> 4;
  const int wm = (wid >> 1) * 64, wn = (wid & 1) * 64;

  __shared__ __align__(16) short As[128 * 64];
  __shared__ __align__(16) short Bs[128 * 64];

  const bf16* iB = imgT + (size_t)bI * MM * CC;

  f32x4 acc[4][4];
#pragma unroll
  for (int mi = 0; mi < 4; ++mi)
#pragma unroll
    for (int ni = 0; ni < 4; ++ni) acc[mi][ni] = (f32x4){0.f, 0.f, 0.f, 0.f};

  const int srow = lane >> 3;
  const int skc = (lane & 7) * 8;

  for (int kt = 0; kt < 4; ++kt) {
    const int k0 = kt * 64;
#pragma unroll
    for (int cc = 0; cc < 4; ++cc) {
      const int c = wid * 4 + cc;
      const int r = c * 8 + srow;
      GLOAD16(wb + (size_t)(o0 + r) * CC + k0 + skc, &As[c * 512]);
      GLOAD16(iB + (size_t)(m0 + r) * CC + k0 + skc, &Bs[c * 512]);
    }
    __syncthreads();
    bf16x8 af[4][2], bfr[4][2];
#pragma unroll
    for (int mi = 0; mi < 4; ++mi)
#pragma unroll
      for (int kkk = 0; kkk < 2; ++kkk)
        af[mi][kkk] = *(const bf16x8*)&As[(wm + mi * 16 + fr) * 64 + kkk * 32 + fq * 8];
#pragma unroll
    for (int ni = 0; ni < 4; ++ni)
#pragma unroll
      for (int kkk = 0; kkk < 2; ++kkk)
        bfr[ni][kkk] = *(const bf16x8*)&Bs[(wn + ni * 16 + fr) * 64 + kkk * 32 + fq * 8];
#pragma unroll
    for (int mi = 0; mi < 4; ++mi)
#pragma unroll
      for (int ni = 0; ni < 4; ++ni)
#pragma unroll
        for (int kkk = 0; kkk < 2; ++kkk)
          acc[mi][ni] = __builtin_amdgcn_mfma_f32_16x16x32_bf16(af[mi][kkk], bfr[ni][kkk], acc[mi][ni], 0, 0, 0);
    __syncthreads();
  }

#pragma unroll
  for (int mi = 0; mi < 4; ++mi) {
#pragma unroll
    for (int ni = 0; ni < 4; ++ni) {
      const int mcol = m0 + wn + ni * 16 + fr;
#pragma unroll
      for (int r = 0; r < 4; ++r) {
        int oo = o0 + wm + mi * 16 + fq * 4 + r;
        bf16* dst;
        if (oo < 512) { dst = q; }
        else if (oo < 1024) { dst = kk; oo -= 512; }
        else { dst = v; oo -= 1024; }
        dst[((size_t)bI * 512 + oo) * MM + mcol] = f2b(acc[mi][ni][r]);
      }
    }
  }
}

// ---------------------------------------------------------------------------
// K2: in-place softmax over m=4096 per (n,d) row
// ---------------------------------------------------------------------------
__global__ __launch_bounds__(256) void k_softmax(bf16* __restrict__ kk) {
  const size_t row = blockIdx.x;
  bf16* p = kk + row * (size_t)MM;
  const int t = threadIdx.x;
  __shared__ float sred[4];
  float mx = -1e30f;
  for (int i = t; i < MM; i += 256) mx = fmaxf(mx, b2f(p[i]));
#pragma unroll
  for (int off = 32; off; off >>= 1) mx = fmaxf(mx, __shfl_down(mx, off));
  if ((t & 63) == 0) sred[t >> 6] = mx;
  __syncthreads();
  mx = fmaxf(fmaxf(sred[0], sred[1]), fmaxf(sred[2], sred[3]));
  __syncthreads();
  float s = 0.f;
  for (int i = t; i < MM; i += 256) { float e = expf(b2f(p[i]) - mx); p[i] = f2b(e); s += e; }
#pragma unroll
  for (int off = 32; off; off >>= 1) s += __shfl_down(s, off);
  if ((t & 63) == 0) sred[t >> 6] = s;
  __syncthreads();
  s = sred[0] + sred[1] + sred[2] + sred[3];
  const float inv = 1.0f / s;
  for (int i = t; i < MM; i += 256) p[i] = f2b(b2f(p[i]) * inv);
}

// ---------------------------------------------------------------------------
// K3a: partial context[n,d,e] = sum_m k[n,d,m]*v[n,e,m]
// ---------------------------------------------------------------------------
__global__ __launch_bounds__(256) void k_ctx_part(const bf16* __restrict__ kk, const bf16* __restrict__ v,
                                                  float* __restrict__ part) {
  const int ch = blockIdx.x, n = blockIdx.y;
  const int tx = threadIdx.x, ty = threadIdx.y;
  const int tid = ty * 16 + tx;
  __shared__ float Ks[64][65];
  __shared__ float Vs[64][65];
  float acc[4][4] = {};
  const bf16* kp = kk + (size_t)n * DKC * MM;
  const bf16* vp = v + (size_t)n * DKC * MM;
  for (int m0 = ch * 512; m0 < ch * 512 + 512; m0 += 64) {
#pragma unroll
    for (int l = 0; l < 16; ++l) {
      int e = tid + l * 256;
      int d = e >> 6, j = e & 63;
      Ks[d][j] = b2f(kp[(size_t)d * MM + m0 + j]);
      Vs[d][j] = b2f(vp[(size_t)d * MM + m0 + j]);
    }
    __syncthreads();
#pragma unroll
    for (int j = 0; j < 64; ++j) {
      float a[4], bbv[4];
#pragma unroll
      for (int u = 0; u < 4; ++u) a[u] = Ks[ty * 4 + u][j];
#pragma unroll
      for (int u = 0; u < 4; ++u) bbv[u] = Vs[tx * 4 + u][j];
#pragma unroll
      for (int u = 0; u < 4; ++u)
#pragma unroll
        for (int w2 = 0; w2 < 4; ++w2) acc[u][w2] += a[u] * bbv[w2];
    }
    __syncthreads();
  }
#pragma unroll
  for (int u = 0; u < 4; ++u)
#pragma unroll
    for (int w2 = 0; w2 < 4; ++w2)
      part[((size_t)ch * NH + n) * 4096 + (ty * 4 + u) * 64 + tx * 4 + w2] = acc[u][w2];
}

// K3b: reduce 8 partials
__global__ __launch_bounds__(256) void k_ctx_red(const float* __restrict__ part, float* __restrict__ ctx) {
  const int idx = blockIdx.x * 256 + threadIdx.x;
  float s = 0.f;
#pragma unroll
  for (int c = 0; c < 8; ++c) s += part[(size_t)c * 262144 + idx];
  ctx[idx] = s;
}

// ---------------------------------------------------------------------------
// K4: content path -> contentT[b][m][512] (transposed layout, c = h*64+e)
//   contentT[b][m][h*64+e] = sum_d ctx[n,d,e]*q[n,d,m]
// grid (64 mt, 64 n), block (16,16)
// ---------------------------------------------------------------------------
__global__ __launch_bounds__(256) void k_content(const float* __restrict__ ctx, const bf16* __restrict__ q,
                                                 bf16* __restrict__ contentT) {
  const int m0 = blockIdx.x * 64, n = blockIdx.y;
  const int bI = n >> 3, h = n & 7;
  const int tx = threadIdx.x, ty = threadIdx.y;
  const int tid = ty * 16 + tx;
  __shared__ float Cs[64][65];
  __shared__ float Qs[64][65];
  const float* cn = ctx + (size_t)n * 4096;
  const bf16* qn = q + (size_t)n * DKC * MM;
#pragma unroll
  for (int l = 0; l < 16; ++l) {
    int e = tid + l * 256;
    int d = e >> 6, j = e & 63;
    Cs[d][j] = cn[e];
    Qs[d][j] = b2f(qn[(size_t)d * MM + m0 + j]);
  }
  __syncthreads();
  float acc[4][4] = {};
#pragma unroll 8
  for (int d = 0; d < 64; ++d) {
    float a[4], bbv[4];
#pragma unroll
    for (int u = 0; u < 4; ++u) a[u] = Cs[d][ty * 4 + u];
#pragma unroll
    for (int u = 0; u < 4; ++u) bbv[u] = Qs[d][tx * 4 + u];
#pragma unroll
    for (int u = 0; u < 4; ++u)
#pragma unroll
      for (int w2 = 0; w2 < 4; ++w2) acc[u][w2] += a[u] * bbv[w2];
  }
  bf16* cb = contentT + (size_t)bI * MM * 512;
#pragma unroll
  for (int w2 = 0; w2 < 4; ++w2) {
    u16x4 pk;
#pragma unroll
    for (int u = 0; u < 4; ++u) pk[u] = bbits(acc[u][w2]);
    *(u16x4*)&cb[(size_t)(m0 + 4 * tx + w2) * 512 + h * 64 + 4 * ty] = pk;
  }
}

// ---------------------------------------------------------------------------
// K5a: k_sx — rel-row stage 1: Sx[n][x][i][y] = sum_d relr[i-x+63][d]*q[n,d,x*64+y]
// ---------------------------------------------------------------------------
__global__ __launch_bounds__(256) void k_sx(const float* __restrict__ relr, const bf16* __restrict__ q,
                                            bf16* __restrict__ sx) {
  const int x = blockIdx.x, n = blockIdx.y;
  const int tx = threadIdx.x, ty = threadIdx.y;
  const int tid = ty * 16 + tx;
  __shared__ float Af[64 * 66];   // Af[d][i] = relr[i+63-x][d]
  __shared__ bf16 Qs[64 * 66];    // Qs[d][y]
  const size_t nb = (size_t)n * DKC * MM;
  for (int t = tid; t < 4096; t += 256) {
    int i = t >> 6, d = t & 63;
    Af[d * 66 + i] = relr[(i + 63 - x) * 64 + d];
  }
  for (int t = tid; t < 4096; t += 256) {
    int d = t >> 6, y = t & 63;
    Qs[d * 66 + y] = q[nb + (size_t)d * MM + x * 64 + y];
  }
  __syncthreads();
  float acc[4][4] = {};
#pragma unroll 8
  for (int d = 0; d < 64; ++d) {
    float a[4], b[4];
#pragma unroll
    for (int u = 0; u < 4; ++u) a[u] = Af[d * 66 + 4 * ty + u];
#pragma unroll
    for (int w2 = 0; w2 < 4; ++w2) b[w2] = b2f(Qs[d * 66 + 4 * tx + w2]);
#pragma unroll
    for (int u = 0; u < 4; ++u)
#pragma unroll
      for (int w2 = 0; w2 < 4; ++w2) acc[u][w2] += a[u] * b[w2];
  }
  const size_t sxbase = ((size_t)(n * 64 + x)) * 4096;
#pragma unroll
  for (int u = 0; u < 4; ++u) {
    u16x4 pk;
#pragma unroll
    for (int w2 = 0; w2 < 4; ++w2) pk[w2] = bbits(acc[u][w2]);
    *(u16x4*)&sx[sxbase + (size_t)(4 * ty + u) * 64 + 4 * tx] = pk;
  }
}

// ---------------------------------------------------------------------------
// K5b: k_yh — rel-row stage 2: Yh[n,e,x,y] = sum_i v[n,e,i*64+y]*Sx[n,x,i,y]
// ---------------------------------------------------------------------------
__global__ __launch_bounds__(256) void k_yh(const bf16* __restrict__ v, const bf16* __restrict__ sx,
                                            bf16* __restrict__ yh) {
  const int xg = blockIdx.x, et = blockIdx.y, n = blockIdx.z;
  const int y = threadIdx.x, s = threadIdx.y;
  const int eb = et * 16 + s * 4;
  const size_t nb = (size_t)n * DKC * MM;
  const bf16* vp = v + nb;
  const bf16* sp = sx + ((size_t)(n * 64 + xg * 8)) * 4096;
  float acc[4][8] = {};
#pragma unroll 4
  for (int i = 0; i < 64; ++i) {
    float vv[4], ss[8];
#pragma unroll
    for (int ee = 0; ee < 4; ++ee) vv[ee] = b2f(vp[(size_t)(eb + ee) * MM + i * 64 + y]);
#pragma unroll
    for (int xx = 0; xx < 8; ++xx) ss[xx] = b2f(sp[(size_t)(xx * 64 + i) * 64 + y]);
#pragma unroll
    for (int ee = 0; ee < 4; ++ee)
#pragma unroll
      for (int xx = 0; xx < 8; ++xx) acc[ee][xx] += vv[ee] * ss[xx];
  }
#pragma unroll
  for (int ee = 0; ee < 4; ++ee)
#pragma unroll
    for (int xx = 0; xx < 8; ++xx)
      yh[nb + (size_t)(eb + ee) * MM + (xg * 8 + xx) * 64 + y] = f2b(acc[ee][xx]);
}

// ---------------------------------------------------------------------------
// K6a: BN partial stats per (e, n-group of 8)
// ---------------------------------------------------------------------------
__global__ __launch_bounds__(256) void k_bnpart(const bf16* __restrict__ yh, float* __restrict__ ps,
                                                float* __restrict__ ps2) {
  const int e = blockIdx.x, g = blockIdx.y;
  const int t = threadIdx.x;
  float s = 0.f, s2 = 0.f;
  for (int nn = g * 8; nn < g * 8 + 8; ++nn) {
    const bf16* p = yh + (size_t)nn * DKC * MM + (size_t)e * MM;
    for (int i = t; i < MM; i += 256) { float x = b2f(p[i]); s += x; s2 += x * x; }
  }
#pragma unroll
  for (int off = 32; off; off >>= 1) { s += __shfl_down(s, off); s2 += __shfl_down(s2, off); }
  __shared__ float r1[4], r2[4];
  if ((t & 63) == 0) { r1[t >> 6] = s; r2[t >> 6] = s2; }
  __syncthreads();
  if (t == 0) {
    ps[e * 8 + g] = r1[0] + r1[1] + r1[2] + r1[3];
    ps2[e * 8 + g] = r2[0] + r2[1] + r2[2] + r2[3];
  }
}

// K6b: finalize BN stats
__global__ __launch_bounds__(64) void k_bnfin(const float* __restrict__ ps, const float* __restrict__ ps2,
                                              float* __restrict__ mu, float* __restrict__ rs) {
  const int e = threadIdx.x;
  float S = 0.f, S2 = 0.f;
#pragma unroll
  for (int g = 0; g < 8; ++g) { S += ps[e * 8 + g]; S2 += ps2[e * 8 + g]; }
  const float invN = 1.0f / (NH * (float)MM);
  float m = S * invN;
  float var = S2 * invN - m * m;
  mu[e] = m;
  rs[e] = 1.0f / sqrtf(var + 1e-5f);
}

// ---------------------------------------------------------------------------
// K7: k_relcol2 — fused rel-col per (n,x), accumulates into contentT layout:
//   Sc'[j][y] = sum_d relc[j][d]*q[n,d,x*64+y]
//   contentT[b][x*64+y][h*64+e] += sum_i BN(yh[n,e,x*64+i]) * Sc'[i-y+63][y]
// ---------------------------------------------------------------------------
__global__ __launch_bounds__(256) void k_relcol2(const bf16* __restrict__ q, const bf16* __restrict__ yh,
                                                 const float* __restrict__ relc, const float* __restrict__ mu,
                                                 const float* __restrict__ rs, const float* __restrict__ gamma,
                                                 const float* __restrict__ beta, bf16* __restrict__ contentT) {
  const int xx = blockIdx.x, n = blockIdx.y;
  const int bI = n >> 3, h = n & 7;
  const int tx = threadIdx.x, ty = threadIdx.y;
  const int tid = ty * 16 + tx;
  __shared__ __align__(16) unsigned char smem[16640 + 8448 + 33528];
  bf16* Ab = (bf16*)smem;                    // [64][130] A^T: Ab[d][j]=relc[j][d]
  bf16* Qs = (bf16*)(smem + 16640);          // [64][66]
  float* Sc = (float*)(smem + 16640 + 8448); // [127][66]
  float* Ys = (float*)smem;                  // overlay on Ab after stage 1: [64][65]
  const size_t nb = (size_t)n * DKC * MM;

  for (int t = tid; t < RRN * 64; t += 256) {
    int j = t >> 6, d = t & 63;
    Ab[d * 130 + j] = f2b(relc[t]);
  }
  for (int t = tid; t < 4096; t += 256) {
    int d = t >> 6, y = t & 63;
    Qs[d * 66 + y] = q[nb + (size_t)d * MM + xx * 64 + y];
  }
  __syncthreads();

  // stage 1: Sc'[j][y], j = ty + 16u
  float acc1[8][4] = {};
#pragma unroll 8
  for (int d = 0; d < 64; ++d) {
    float a[8], b[4];
#pragma unroll
    for (int u = 0; u < 8; ++u) a[u] = b2f(Ab[d * 130 + ty + 16 * u]);
#pragma unroll
    for (int w2 = 0; w2 < 4; ++w2) b[w2] = b2f(Qs[d * 66 + 4 * tx + w2]);
#pragma unroll
    for (int u = 0; u < 8; ++u)
#pragma unroll
      for (int w2 = 0; w2 < 4; ++w2) acc1[u][w2] += a[u] * b[w2];
  }
#pragma unroll
  for (int u = 0; u < 8; ++u) {
    int j = ty + 16 * u;
    if (j < RRN) {
#pragma unroll
      for (int w2 = 0; w2 < 4; ++w2) Sc[j * 66 + 4 * tx + w2] = acc1[u][w2];
    }
  }
  __syncthreads();

  // stage Ys = BN(yh) into overlay
  for (int t = tid; t < 4096; t += 256) {
    int e = t >> 6, i = t & 63;
    Ys[e * 65 + i] = (b2f(yh[nb + (size_t)e * MM + xx * 64 + i]) - mu[e]) * rs[e] * gamma[e] + beta[e];
  }
  __syncthreads();

  // stage 2: out[e][y] += sum_i Ys[e][i] * Sc[i-y+63][y]
  float acc2[4][4] = {};
#pragma unroll 8
  for (int i = 0; i < 64; ++i) {
    float yv[4], sv[4];
#pragma unroll
    for (int u = 0; u < 4; ++u) yv[u] = Ys[(4 * ty + u) * 65 + i];
#pragma unroll
    for (int w2 = 0; w2 < 4; ++w2) {
      int y = 4 * tx + w2;
      sv[w2] = Sc[(i - y + 63) * 66 + y];
    }
#pragma unroll
    for (int u = 0; u < 4; ++u)
#pragma unroll
      for (int w2 = 0; w2 < 4; ++w2) acc2[u][w2] += yv[u] * sv[w2];
  }
  // RMW into contentT[b][m=xx*64+y][c=h*64+e], packed 4-consecutive-c per store
  bf16* cb = contentT + (size_t)bI * MM * 512;
#pragma unroll
  for (int w2 = 0; w2 < 4; ++w2) {
    size_t a = (size_t)(xx * 64 + 4 * tx + w2) * 512 + h * 64 + 4 * ty;
    u16x4 pk = *(u16x4*)&cb[a];
#pragma unroll
    for (int u = 0; u < 4; ++u) pk[u] = bbits(fbits(pk[u]) + acc2[u][w2]);
    *(u16x4*)&cb[a] = pk;
  }
}

// ---------------------------------------------------------------------------
// K8: MFMA final GEMM: out[b][o][m] = sum_k wout[o][k]*contentT[b][m][k] + bias
// 128x128 tile, BK=64, 8 k-tiles (K=512), 4 waves. grid (32 mt, 2 ot, 8 b)
// ---------------------------------------------------------------------------
__global__ __launch_bounds__(256) void k_final(const bf16* __restrict__ wb2, const bf16* __restrict__ cT,
                                               const float* __restrict__ bout, float* __restrict__ dout) {
  const int bI = blockIdx.z;
  const int o0 = blockIdx.y * 128;
  const int m0 = blockIdx.x * 128;
  const int tid = threadIdx.x;
  const int lane = tid & 63, wid = tid >> 6;
  const int fr = lane & 15;
  const int fq = lane >> 4;
  const int wm = (wid >> 1) * 64, wn = (wid & 1) * 64;

  __shared__ __align__(16) short As[128 * 64];
  __shared__ __align__(16) short Bs[128 * 64];

  const bf16* cB = cT + (size_t)bI * MM * 512;

  f32x4 acc[4][4];
#pragma unroll
  for (int mi = 0; mi < 4; ++mi)
#pragma unroll
    for (int ni = 0; ni < 4; ++ni) acc[mi][ni] = (f32x4){0.f, 0.f, 0.f, 0.f};

  const int srow = lane >> 3;
  const int skc = (lane & 7) * 8;

  for (int kt = 0; kt < 8; ++kt) {
    const int k0 = kt * 64;
#pragma unroll
    for (int cc = 0; cc < 4; ++cc) {
      const int c = wid * 4 + cc;
      const int r = c * 8 + srow;
      GLOAD16(wb2 + (size_t)(o0 + r) * 512 + k0 + skc, &As[c * 512]);
      GLOAD16(cB + (size_t)(m0 + r) * 512 + k0 + skc, &Bs[c * 512]);
    }
    __syncthreads();
    bf16x8 af[4][2], bfr[4][2];
#pragma unroll
    for (int mi = 0; mi < 4; ++mi)
#pragma unroll
      for (int kkk = 0; kkk < 2; ++kkk)
        af[mi][kkk] = *(const bf16x8*)&As[(wm + mi * 16 + fr) * 64 + kkk * 32 + fq * 8];
#pragma unroll
    for (int ni = 0; ni < 4; ++ni)
#pragma unroll
      for (int kkk = 0; kkk < 2; ++kkk)
        bfr[ni][kkk] = *(const bf16x8*)&Bs[(wn + ni * 16 + fr) * 64 + kkk * 32 + fq * 8];
#pragma unroll
    for (int mi = 0; mi < 4; ++mi)
#pragma unroll
      for (int ni = 0; ni < 4; ++ni)
#pragma unroll
        for (int kkk = 0; kkk < 2; ++kkk)
          acc[mi][ni] = __builtin_amdgcn_mfma_f32_16x16x32_bf16(af[mi][kkk], bfr[ni][kkk], acc[mi][ni], 0, 0, 0);
    __syncthreads();
  }

#pragma unroll
  for (int mi = 0; mi < 4; ++mi) {
#pragma unroll
    for (int ni = 0; ni < 4; ++ni) {
      const int mcol = m0 + wn + ni * 16 + fr;
#pragma unroll
      for (int r = 0; r < 4; ++r) {
        const int oo = o0 + wm + mi * 16 + fq * 4 + r;
        dout[((size_t)bI * 256 + oo) * MM + mcol] = acc[mi][ni][r] + bout[oo];
      }
    }
  }
}

// ---------------------------------------------------------------------------
extern "C" void kernel_launch(void* const* d_in, const int* in_sizes, int n_in,
                              void* d_out, int out_size, void* d_ws, size_t ws_size,
                              hipStream_t stream) {
  const float* img = (const float*)d_in[0];
  const float* w_qkv = (const float*)d_in[1];
  const float* w_out = (const float*)d_in[2];
  const float* b_out = (const float*)d_in[3];
  const float* rel_rows = (const float*)d_in[4];
  const float* rel_cols = (const float*)d_in[5];
  const float* gamma = (const float*)d_in[6];
  const float* beta = (const float*)d_in[7];
  float* out = (float*)d_out;

  const size_t SZ = (size_t)NH * DKC * MM;  // 16,777,216 elements
  bf16* q = (bf16*)d_ws;          // SZ bf16
  bf16* kbuf = q + SZ;            // SZ bf16: k, later reused as yh
  bf16* vbuf = kbuf + SZ;         // SZ bf16: v, later reused as contentT [b][m][512]
  bf16* imgT = vbuf + SZ;         // 8,388,608 bf16, dead after k_qkv
  // union region overlaid on imgT (alive only after k_qkv):
  float* ctxp = (float*)imgT;     // 2,097,152 f32
  float* ctx = ctxp + 2097152;    // 262,144 f32
  float* ps = ctx + 262144;       // 512
  float* ps2 = ps + 512;          // 512
  float* mu = ps2 + 512;          // 64
  float* rs = mu + 64;            // 64
  bf16* wb = imgT + 8388608;      // 393,216 bf16
  bf16* sxbuf = wb + 393216;      // SZ bf16 (33.5 MB)
  bf16* wb2 = sxbuf + SZ;         // 131,072 bf16 (w_out)
  // total ~152 MB

  k_cvt_w<<<1536, 256, 0, stream>>>(w_qkv, wb);
  k_cvt_w2<<<512, 256, 0, stream>>>(w_out, wb2);
  k_timg<<<dim3(64, 4, 8), 256, 0, stream>>>(img, imgT);
  k_qkv<<<dim3(32, 12, 8), 256, 0, stream>>>(wb, imgT, q, kbuf, vbuf);
  k_softmax<<<4096, 256, 0, stream>>>(kbuf);
  k_ctx_part<<<dim3(8, 64), dim3(16, 16), 0, stream>>>(kbuf, vbuf, ctxp);
  k_ctx_red<<<1024, 256, 0, stream>>>(ctxp, ctx);
  // rel-row path (kbuf dead -> becomes yh)
  k_sx<<<dim3(64, 64), dim3(16, 16), 0, stream>>>(rel_rows, q, sxbuf);
  k_yh<<<dim3(8, 4, 64), dim3(64, 4), 0, stream>>>(vbuf, sxbuf, kbuf);
  k_bnpart<<<dim3(64, 8), 256, 0, stream>>>(kbuf, ps, ps2);
  k_bnfin<<<1, 64, 0, stream>>>(ps, ps2, mu, rs);
  // v dead -> vbuf becomes contentT [b][m][512]
  k_content<<<dim3(64, 64), dim3(16, 16), 0, stream>>>(ctx, q, vbuf);
  k_relcol2<<<dim3(64, 64), dim3(16, 16), 0, stream>>>(q, kbuf, rel_cols, mu, rs, gamma, beta, vbuf);
  k_final<<<dim3(32, 2, 8), 256, 0, stream>>>(wb2, vbuf, b_out, out);
}

// Round 6
// 374.538 us; speedup vs baseline: 3.2733x; 1.3012x over previous
//
#include <hip/hip_runtime.h>
#include <hip/hip_bf16.h>
#include <math.h>

// Problem constants
#define NH   64     // b*H heads
#define DKC  64     // dim per head
#define MM   4096   // x*y
#define CC   256    // img channels
#define RRN  127    // 2L-1

typedef __hip_bfloat16 bf16;
__device__ __forceinline__ float b2f(bf16 x) { return __bfloat162float(x); }
__device__ __forceinline__ bf16 f2b(float x) { return __float2bfloat16(x); }
__device__ __forceinline__ unsigned short bbits(float x) { bf16 h = f2b(x); return *(unsigned short*)&h; }
__device__ __forceinline__ float fbits(unsigned short u) { bf16 h = *(bf16*)&u; return b2f(h); }

typedef short bf16x8 __attribute__((ext_vector_type(8)));
typedef float f32x4 __attribute__((ext_vector_type(4)));
typedef unsigned short u16;
typedef u16 u16x4 __attribute__((ext_vector_type(4)));

#define AS1 __attribute__((address_space(1)))
#define AS3 __attribute__((address_space(3)))
#define GLOAD16(gp, lp) __builtin_amdgcn_global_load_lds((const AS1 void*)(gp), (AS3 void*)(lp), 16, 0, 0)

// ---------------------------------------------------------------------------
// K0a: convert w_qkv fp32 -> bf16 (393216 elems)
// ---------------------------------------------------------------------------
__global__ __launch_bounds__(256) void k_cvt_w(const float* __restrict__ w, bf16* __restrict__ wb) {
  const int i = blockIdx.x * 256 + threadIdx.x;
  wb[i] = f2b(w[i]);
}

// K0c: convert w_out fp32 -> bf16 (131072 elems)
__global__ __launch_bounds__(256) void k_cvt_w2(const float* __restrict__ w, bf16* __restrict__ wb) {
  const int i = blockIdx.x * 256 + threadIdx.x;
  wb[i] = f2b(w[i]);
}

// K0d: convert rel_cols fp32 (127x64) -> bf16 padded to 128 rows (row 127 = 0)
__global__ __launch_bounds__(256) void k_cvt_rel(const float* __restrict__ r, bf16* __restrict__ rb) {
  const int i = blockIdx.x * 256 + threadIdx.x;  // grid covers 8192
  rb[i] = (i < RRN * 64) ? f2b(r[i]) : f2b(0.f);
}

// ---------------------------------------------------------------------------
// K0b: img fp32 [8][256][4096] -> bf16 imgT [8][4096][256]
// ---------------------------------------------------------------------------
__global__ __launch_bounds__(256) void k_timg(const float* __restrict__ img, bf16* __restrict__ imgT) {
  const int b = blockIdx.z, c0 = blockIdx.y * 64, m0 = blockIdx.x * 64;
  const int tid = threadIdx.x;
  __shared__ bf16 T[64][65];
  const float* ib = img + ((size_t)b * CC + c0) * MM + m0;
#pragma unroll
  for (int l = 0; l < 16; ++l) {
    int e = tid + l * 256;
    int cc = e >> 6, mm = e & 63;
    T[cc][mm] = f2b(ib[(size_t)cc * MM + mm]);
  }
  __syncthreads();
  bf16* ob = imgT + ((size_t)b * MM + m0) * CC + c0;
#pragma unroll
  for (int l = 0; l < 16; ++l) {
    int e = tid + l * 256;
    int mm = e >> 6, cc = e & 63;
    ob[(size_t)mm * CC + cc] = T[cc][mm];
  }
}

// ---------------------------------------------------------------------------
// K1: MFMA qkv GEMM (128x128 tile, BK=64, 4 waves)
// ---------------------------------------------------------------------------
__global__ __launch_bounds__(256) void k_qkv(const bf16* __restrict__ wb, const bf16* __restrict__ imgT,
                                             bf16* __restrict__ q, bf16* __restrict__ kk, bf16* __restrict__ v) {
  const int bI = blockIdx.z;
  const int o0 = blockIdx.y * 128;
  const int m0 = blockIdx.x * 128;
  const int tid = threadIdx.x;
  const int lane = tid & 63, wid = tid >> 6;
  const int fr = lane & 15;
  const int fq = lane >> 4;
  const int wm = (wid >> 1) * 64, wn = (wid & 1) * 64;

  __shared__ __align__(16) short As[128 * 64];
  __shared__ __align__(16) short Bs[128 * 64];

  const bf16* iB = imgT + (size_t)bI * MM * CC;

  f32x4 acc[4][4];
#pragma unroll
  for (int mi = 0; mi < 4; ++mi)
#pragma unroll
    for (int ni = 0; ni < 4; ++ni) acc[mi][ni] = (f32x4){0.f, 0.f, 0.f, 0.f};

  const int srow = lane >> 3;
  const int skc = (lane & 7) * 8;

  for (int kt = 0; kt < 4; ++kt) {
    const int k0 = kt * 64;
#pragma unroll
    for (int cc = 0; cc < 4; ++cc) {
      const int c = wid * 4 + cc;
      const int r = c * 8 + srow;
      GLOAD16(wb + (size_t)(o0 + r) * CC + k0 + skc, &As[c * 512]);
      GLOAD16(iB + (size_t)(m0 + r) * CC + k0 + skc, &Bs[c * 512]);
    }
    __syncthreads();
    bf16x8 af[4][2], bfr[4][2];
#pragma unroll
    for (int mi = 0; mi < 4; ++mi)
#pragma unroll
      for (int kkk = 0; kkk < 2; ++kkk)
        af[mi][kkk] = *(const bf16x8*)&As[(wm + mi * 16 + fr) * 64 + kkk * 32 + fq * 8];
#pragma unroll
    for (int ni = 0; ni < 4; ++ni)
#pragma unroll
      for (int kkk = 0; kkk < 2; ++kkk)
        bfr[ni][kkk] = *(const bf16x8*)&Bs[(wn + ni * 16 + fr) * 64 + kkk * 32 + fq * 8];
#pragma unroll
    for (int mi = 0; mi < 4; ++mi)
#pragma unroll
      for (int ni = 0; ni < 4; ++ni)
#pragma unroll
        for (int kkk = 0; kkk < 2; ++kkk)
          acc[mi][ni] = __builtin_amdgcn_mfma_f32_16x16x32_bf16(af[mi][kkk], bfr[ni][kkk], acc[mi][ni], 0, 0, 0);
    __syncthreads();
  }

#pragma unroll
  for (int mi = 0; mi < 4; ++mi) {
#pragma unroll
    for (int ni = 0; ni < 4; ++ni) {
      const int mcol = m0 + wn + ni * 16 + fr;
#pragma unroll
      for (int r = 0; r < 4; ++r) {
        int oo = o0 + wm + mi * 16 + fq * 4 + r;
        bf16* dst;
        if (oo < 512) { dst = q; }
        else if (oo < 1024) { dst = kk; oo -= 512; }
        else { dst = v; oo -= 1024; }
        dst[((size_t)bI * 512 + oo) * MM + mcol] = f2b(acc[mi][ni][r]);
      }
    }
  }
}

// ---------------------------------------------------------------------------
// K2: in-place softmax over m=4096 per (n,d) row
// ---------------------------------------------------------------------------
__global__ __launch_bounds__(256) void k_softmax(bf16* __restrict__ kk) {
  const size_t row = blockIdx.x;
  bf16* p = kk + row * (size_t)MM;
  const int t = threadIdx.x;
  __shared__ float sred[4];
  float mx = -1e30f;
  for (int i = t; i < MM; i += 256) mx = fmaxf(mx, b2f(p[i]));
#pragma unroll
  for (int off = 32; off; off >>= 1) mx = fmaxf(mx, __shfl_down(mx, off));
  if ((t & 63) == 0) sred[t >> 6] = mx;
  __syncthreads();
  mx = fmaxf(fmaxf(sred[0], sred[1]), fmaxf(sred[2], sred[3]));
  __syncthreads();
  float s = 0.f;
  for (int i = t; i < MM; i += 256) { float e = expf(b2f(p[i]) - mx); p[i] = f2b(e); s += e; }
#pragma unroll
  for (int off = 32; off; off >>= 1) s += __shfl_down(s, off);
  if ((t & 63) == 0) sred[t >> 6] = s;
  __syncthreads();
  s = sred[0] + sred[1] + sred[2] + sred[3];
  const float inv = 1.0f / s;
  for (int i = t; i < MM; i += 256) p[i] = f2b(b2f(p[i]) * inv);
}

// ---------------------------------------------------------------------------
// K3a: partial context[n,d,e] = sum_m k[n,d,m]*v[n,e,m]
// ---------------------------------------------------------------------------
__global__ __launch_bounds__(256) void k_ctx_part(const bf16* __restrict__ kk, const bf16* __restrict__ v,
                                                  float* __restrict__ part) {
  const int ch = blockIdx.x, n = blockIdx.y;
  const int tx = threadIdx.x, ty = threadIdx.y;
  const int tid = ty * 16 + tx;
  __shared__ float Ks[64][65];
  __shared__ float Vs[64][65];
  float acc[4][4] = {};
  const bf16* kp = kk + (size_t)n * DKC * MM;
  const bf16* vp = v + (size_t)n * DKC * MM;
  for (int m0 = ch * 512; m0 < ch * 512 + 512; m0 += 64) {
#pragma unroll
    for (int l = 0; l < 16; ++l) {
      int e = tid + l * 256;
      int d = e >> 6, j = e & 63;
      Ks[d][j] = b2f(kp[(size_t)d * MM + m0 + j]);
      Vs[d][j] = b2f(vp[(size_t)d * MM + m0 + j]);
    }
    __syncthreads();
#pragma unroll
    for (int j = 0; j < 64; ++j) {
      float a[4], bbv[4];
#pragma unroll
      for (int u = 0; u < 4; ++u) a[u] = Ks[ty * 4 + u][j];
#pragma unroll
      for (int u = 0; u < 4; ++u) bbv[u] = Vs[tx * 4 + u][j];
#pragma unroll
      for (int u = 0; u < 4; ++u)
#pragma unroll
        for (int w2 = 0; w2 < 4; ++w2) acc[u][w2] += a[u] * bbv[w2];
    }
    __syncthreads();
  }
#pragma unroll
  for (int u = 0; u < 4; ++u)
#pragma unroll
    for (int w2 = 0; w2 < 4; ++w2)
      part[((size_t)ch * NH + n) * 4096 + (ty * 4 + u) * 64 + tx * 4 + w2] = acc[u][w2];
}

// K3b: reduce 8 partials
__global__ __launch_bounds__(256) void k_ctx_red(const float* __restrict__ part, float* __restrict__ ctx) {
  const int idx = blockIdx.x * 256 + threadIdx.x;
  float s = 0.f;
#pragma unroll
  for (int c = 0; c < 8; ++c) s += part[(size_t)c * 262144 + idx];
  ctx[idx] = s;
}

// ---------------------------------------------------------------------------
// K4: content path -> contentT[b][m][512] (transposed layout, c = h*64+e)
// ---------------------------------------------------------------------------
__global__ __launch_bounds__(256) void k_content(const float* __restrict__ ctx, const bf16* __restrict__ q,
                                                 bf16* __restrict__ contentT) {
  const int m0 = blockIdx.x * 64, n = blockIdx.y;
  const int bI = n >> 3, h = n & 7;
  const int tx = threadIdx.x, ty = threadIdx.y;
  const int tid = ty * 16 + tx;
  __shared__ float Cs[64][65];
  __shared__ float Qs[64][65];
  const float* cn = ctx + (size_t)n * 4096;
  const bf16* qn = q + (size_t)n * DKC * MM;
#pragma unroll
  for (int l = 0; l < 16; ++l) {
    int e = tid + l * 256;
    int d = e >> 6, j = e & 63;
    Cs[d][j] = cn[e];
    Qs[d][j] = b2f(qn[(size_t)d * MM + m0 + j]);
  }
  __syncthreads();
  float acc[4][4] = {};
#pragma unroll 8
  for (int d = 0; d < 64; ++d) {
    float a[4], bbv[4];
#pragma unroll
    for (int u = 0; u < 4; ++u) a[u] = Cs[d][ty * 4 + u];
#pragma unroll
    for (int u = 0; u < 4; ++u) bbv[u] = Qs[d][tx * 4 + u];
#pragma unroll
    for (int u = 0; u < 4; ++u)
#pragma unroll
      for (int w2 = 0; w2 < 4; ++w2) acc[u][w2] += a[u] * bbv[w2];
  }
  bf16* cb = contentT + (size_t)bI * MM * 512;
#pragma unroll
  for (int w2 = 0; w2 < 4; ++w2) {
    u16x4 pk;
#pragma unroll
    for (int u = 0; u < 4; ++u) pk[u] = bbits(acc[u][w2]);
    *(u16x4*)&cb[(size_t)(m0 + 4 * tx + w2) * 512 + h * 64 + 4 * ty] = pk;
  }
}

// ---------------------------------------------------------------------------
// K5a: k_sx — rel-row stage 1: Sx[n][x][i][y] = sum_d relr[i-x+63][d]*q[n,d,x*64+y]
// ---------------------------------------------------------------------------
__global__ __launch_bounds__(256) void k_sx(const float* __restrict__ relr, const bf16* __restrict__ q,
                                            bf16* __restrict__ sx) {
  const int x = blockIdx.x, n = blockIdx.y;
  const int tx = threadIdx.x, ty = threadIdx.y;
  const int tid = ty * 16 + tx;
  __shared__ float Af[64 * 66];   // Af[d][i] = relr[i+63-x][d]
  __shared__ bf16 Qs[64 * 66];    // Qs[d][y]
  const size_t nb = (size_t)n * DKC * MM;
  for (int t = tid; t < 4096; t += 256) {
    int i = t >> 6, d = t & 63;
    Af[d * 66 + i] = relr[(i + 63 - x) * 64 + d];
  }
  for (int t = tid; t < 4096; t += 256) {
    int d = t >> 6, y = t & 63;
    Qs[d * 66 + y] = q[nb + (size_t)d * MM + x * 64 + y];
  }
  __syncthreads();
  float acc[4][4] = {};
#pragma unroll 8
  for (int d = 0; d < 64; ++d) {
    float a[4], b[4];
#pragma unroll
    for (int u = 0; u < 4; ++u) a[u] = Af[d * 66 + 4 * ty + u];
#pragma unroll
    for (int w2 = 0; w2 < 4; ++w2) b[w2] = b2f(Qs[d * 66 + 4 * tx + w2]);
#pragma unroll
    for (int u = 0; u < 4; ++u)
#pragma unroll
      for (int w2 = 0; w2 < 4; ++w2) acc[u][w2] += a[u] * b[w2];
  }
  const size_t sxbase = ((size_t)(n * 64 + x)) * 4096;
#pragma unroll
  for (int u = 0; u < 4; ++u) {
    u16x4 pk;
#pragma unroll
    for (int w2 = 0; w2 < 4; ++w2) pk[w2] = bbits(acc[u][w2]);
    *(u16x4*)&sx[sxbase + (size_t)(4 * ty + u) * 64 + 4 * tx] = pk;
  }
}

// ---------------------------------------------------------------------------
// K5b: k_yh — rel-row stage 2: Yh[n,e,x,y] = sum_i v[n,e,i*64+y]*Sx[n,x,i,y]
// ---------------------------------------------------------------------------
__global__ __launch_bounds__(256) void k_yh(const bf16* __restrict__ v, const bf16* __restrict__ sx,
                                            bf16* __restrict__ yh) {
  const int xg = blockIdx.x, et = blockIdx.y, n = blockIdx.z;
  const int y = threadIdx.x, s = threadIdx.y;
  const int eb = et * 16 + s * 4;
  const size_t nb = (size_t)n * DKC * MM;
  const bf16* vp = v + nb;
  const bf16* sp = sx + ((size_t)(n * 64 + xg * 8)) * 4096;
  float acc[4][8] = {};
#pragma unroll 4
  for (int i = 0; i < 64; ++i) {
    float vv[4], ss[8];
#pragma unroll
    for (int ee = 0; ee < 4; ++ee) vv[ee] = b2f(vp[(size_t)(eb + ee) * MM + i * 64 + y]);
#pragma unroll
    for (int xx = 0; xx < 8; ++xx) ss[xx] = b2f(sp[(size_t)(xx * 64 + i) * 64 + y]);
#pragma unroll
    for (int ee = 0; ee < 4; ++ee)
#pragma unroll
      for (int xx = 0; xx < 8; ++xx) acc[ee][xx] += vv[ee] * ss[xx];
  }
#pragma unroll
  for (int ee = 0; ee < 4; ++ee)
#pragma unroll
    for (int xx = 0; xx < 8; ++xx)
      yh[nb + (size_t)(eb + ee) * MM + (xg * 8 + xx) * 64 + y] = f2b(acc[ee][xx]);
}

// ---------------------------------------------------------------------------
// K6a: BN partial stats per (e, n-group of 8)
// ---------------------------------------------------------------------------
__global__ __launch_bounds__(256) void k_bnpart(const bf16* __restrict__ yh, float* __restrict__ ps,
                                                float* __restrict__ ps2) {
  const int e = blockIdx.x, g = blockIdx.y;
  const int t = threadIdx.x;
  float s = 0.f, s2 = 0.f;
  for (int nn = g * 8; nn < g * 8 + 8; ++nn) {
    const bf16* p = yh + (size_t)nn * DKC * MM + (size_t)e * MM;
    for (int i = t; i < MM; i += 256) { float x = b2f(p[i]); s += x; s2 += x * x; }
  }
#pragma unroll
  for (int off = 32; off; off >>= 1) { s += __shfl_down(s, off); s2 += __shfl_down(s2, off); }
  __shared__ float r1[4], r2[4];
  if ((t & 63) == 0) { r1[t >> 6] = s; r2[t >> 6] = s2; }
  __syncthreads();
  if (t == 0) {
    ps[e * 8 + g] = r1[0] + r1[1] + r1[2] + r1[3];
    ps2[e * 8 + g] = r2[0] + r2[1] + r2[2] + r2[3];
  }
}

// K6b: finalize BN stats
__global__ __launch_bounds__(64) void k_bnfin(const float* __restrict__ ps, const float* __restrict__ ps2,
                                              float* __restrict__ mu, float* __restrict__ rs) {
  const int e = threadIdx.x;
  float S = 0.f, S2 = 0.f;
#pragma unroll
  for (int g = 0; g < 8; ++g) { S += ps[e * 8 + g]; S2 += ps2[e * 8 + g]; }
  const float invN = 1.0f / (NH * (float)MM);
  float m = S * invN;
  float var = S2 * invN - m * m;
  mu[e] = m;
  rs[e] = 1.0f / sqrtf(var + 1e-5f);
}

// ---------------------------------------------------------------------------
// K7: k_relcol3 — MFMA fused rel-col per (n,x):
//   stage1 (MFMA): Sc[j][y] = sum_d relcb[j][d] * Q[y][d]   (j<128 padded, K=64)
//   gather:        DT[y][i] = Sc[i-y+63][y]
//   stage2 (MFMA): out[e][y] = sum_i Ys[e][i] * DT[y][i],  Ys = BN(yh)
//   epilogue: RMW into contentT[b][m][512]
// grid (64 x, 64 n), block 256 (4 waves). LDS 36.9 KB -> 4 blocks/CU.
// ---------------------------------------------------------------------------
__global__ __launch_bounds__(256) void k_relcol3(const bf16* __restrict__ q, const bf16* __restrict__ yh,
                                                 const bf16* __restrict__ relcb, const float* __restrict__ mu,
                                                 const float* __restrict__ rs, const float* __restrict__ gamma,
                                                 const float* __restrict__ beta, bf16* __restrict__ contentT) {
  const int xx = blockIdx.x, n = blockIdx.y;
  const int bI = n >> 3, h = n & 7;
  const int tid = threadIdx.x;
  const int lane = tid & 63, wv = tid >> 6;
  const int fr = lane & 15, fq = lane >> 4;
  __shared__ __align__(16) bf16 smem[4608 + 9216 + 4608];
  bf16* Qt = smem;                  // [64][72] y-major, d XOR-swizzled by 8*(y>>3)
  bf16* Scb = smem + 4608;          // [128][72] j-major
  bf16* Ysb = smem + 4608 + 9216;   // [64][72] e-major
  bf16* DT = smem;                  // overlay on Qt after stage 1

  const size_t nb = (size_t)n * DKC * MM;

  // stage Qt: transpose q[d][xx*64+y] -> Qt[y][d^swz]  (coalesced global reads)
#pragma unroll
  for (int l = 0; l < 16; ++l) {
    int idx = tid + l * 256;
    int d = idx >> 6, y = idx & 63;
    Qt[y * 72 + (d ^ (8 * (y >> 3)))] = q[nb + (size_t)d * MM + xx * 64 + y];
  }
  // stage Ysb = BN(yh)
#pragma unroll
  for (int l = 0; l < 16; ++l) {
    int idx = tid + l * 256;
    int e = idx >> 6, i = idx & 63;
    float val = (b2f(yh[nb + (size_t)e * MM + xx * 64 + i]) - mu[e]) * rs[e] * gamma[e] + beta[e];
    Ysb[e * 72 + i] = f2b(val);
  }
  // stage-1 A fragments (relc rows) straight from global (L1/L2-resident)
  bf16x8 af[2][2];
#pragma unroll
  for (int mi = 0; mi < 2; ++mi)
#pragma unroll
    for (int kk = 0; kk < 2; ++kk)
      af[mi][kk] = *(const bf16x8*)&relcb[(size_t)(wv * 32 + mi * 16 + fr) * 64 + kk * 32 + fq * 8];
  __syncthreads();

  // stage 1 MFMA: wave wv computes j in [wv*32, wv*32+32)
  f32x4 acc1[2][4];
#pragma unroll
  for (int mi = 0; mi < 2; ++mi)
#pragma unroll
    for (int ni = 0; ni < 4; ++ni) acc1[mi][ni] = (f32x4){0.f, 0.f, 0.f, 0.f};
  bf16x8 bq[4][2];
#pragma unroll
  for (int ni = 0; ni < 4; ++ni) {
    const int row = ni * 16 + fr;
    const int swz = 8 * (row >> 3);
#pragma unroll
    for (int kk = 0; kk < 2; ++kk)
      bq[ni][kk] = *(const bf16x8*)&Qt[row * 72 + ((kk * 32 + fq * 8) ^ swz)];
  }
#pragma unroll
  for (int mi = 0; mi < 2; ++mi)
#pragma unroll
    for (int ni = 0; ni < 4; ++ni)
#pragma unroll
      for (int kk = 0; kk < 2; ++kk)
        acc1[mi][ni] = __builtin_amdgcn_mfma_f32_16x16x32_bf16(af[mi][kk], bq[ni][kk], acc1[mi][ni], 0, 0, 0);
  // write Sc[j][y] (bf16)
#pragma unroll
  for (int mi = 0; mi < 2; ++mi)
#pragma unroll
    for (int ni = 0; ni < 4; ++ni)
#pragma unroll
      for (int r = 0; r < 4; ++r)
        Scb[(wv * 32 + mi * 16 + fq * 4 + r) * 72 + ni * 16 + fr] = f2b(acc1[mi][ni][r]);
  __syncthreads();

  // DT[y][i] = Sc[i-y+63][y] (overlay on Qt; Qt fully consumed above)
#pragma unroll
  for (int l = 0; l < 16; ++l) {
    int idx = tid + l * 256;
    int y = idx >> 6, i = idx & 63;
    DT[y * 72 + i] = Scb[(i - y + 63) * 72 + y];
  }
  __syncthreads();

  // stage 2 MFMA: wave wv computes e in [wv*16, wv*16+16)
  bf16x8 a2[2], bd[4][2];
#pragma unroll
  for (int kk = 0; kk < 2; ++kk)
    a2[kk] = *(const bf16x8*)&Ysb[(wv * 16 + fr) * 72 + kk * 32 + fq * 8];
#pragma unroll
  for (int ni = 0; ni < 4; ++ni)
#pragma unroll
    for (int kk = 0; kk < 2; ++kk)
      bd[ni][kk] = *(const bf16x8*)&DT[(ni * 16 + fr) * 72 + kk * 32 + fq * 8];
  f32x4 acc2[4];
#pragma unroll
  for (int ni = 0; ni < 4; ++ni) acc2[ni] = (f32x4){0.f, 0.f, 0.f, 0.f};
#pragma unroll
  for (int ni = 0; ni < 4; ++ni)
#pragma unroll
    for (int kk = 0; kk < 2; ++kk)
      acc2[ni] = __builtin_amdgcn_mfma_f32_16x16x32_bf16(a2[kk], bd[ni][kk], acc2[ni], 0, 0, 0);

  // epilogue: RMW contentT[b][m=xx*64+y][c=h*64+e], e-quad packed
  bf16* cb = contentT + (size_t)bI * MM * 512;
#pragma unroll
  for (int ni = 0; ni < 4; ++ni) {
    size_t a = (size_t)(xx * 64 + ni * 16 + fr) * 512 + h * 64 + wv * 16 + fq * 4;
    u16x4 pk = *(u16x4*)&cb[a];
#pragma unroll
    for (int r = 0; r < 4; ++r) pk[r] = bbits(fbits(pk[r]) + acc2[ni][r]);
    *(u16x4*)&cb[a] = pk;
  }
}

// ---------------------------------------------------------------------------
// K8: MFMA final GEMM: out[b][o][m] = sum_k wout[o][k]*contentT[b][m][k] + bias
// ---------------------------------------------------------------------------
__global__ __launch_bounds__(256) void k_final(const bf16* __restrict__ wb2, const bf16* __restrict__ cT,
                                               const float* __restrict__ bout, float* __restrict__ dout) {
  const int bI = blockIdx.z;
  const int o0 = blockIdx.y * 128;
  const int m0 = blockIdx.x * 128;
  const int tid = threadIdx.x;
  const int lane = tid & 63, wid = tid >> 6;
  const int fr = lane & 15;
  const int fq = lane >> 4;
  const int wm = (wid >> 1) * 64, wn = (wid & 1) * 64;

  __shared__ __align__(16) short As[128 * 64];
  __shared__ __align__(16) short Bs[128 * 64];

  const bf16* cB = cT + (size_t)bI * MM * 512;

  f32x4 acc[4][4];
#pragma unroll
  for (int mi = 0; mi < 4; ++mi)
#pragma unroll
    for (int ni = 0; ni < 4; ++ni) acc[mi][ni] = (f32x4){0.f, 0.f, 0.f, 0.f};

  const int srow = lane >> 3;
  const int skc = (lane & 7) * 8;

  for (int kt = 0; kt < 8; ++kt) {
    const int k0 = kt * 64;
#pragma unroll
    for (int cc = 0; cc < 4; ++cc) {
      const int c = wid * 4 + cc;
      const int r = c * 8 + srow;
      GLOAD16(wb2 + (size_t)(o0 + r) * 512 + k0 + skc, &As[c * 512]);
      GLOAD16(cB + (size_t)(m0 + r) * 512 + k0 + skc, &Bs[c * 512]);
    }
    __syncthreads();
    bf16x8 af[4][2], bfr[4][2];
#pragma unroll
    for (int mi = 0; mi < 4; ++mi)
#pragma unroll
      for (int kkk = 0; kkk < 2; ++kkk)
        af[mi][kkk] = *(const bf16x8*)&As[(wm + mi * 16 + fr) * 64 + kkk * 32 + fq * 8];
#pragma unroll
    for (int ni = 0; ni < 4; ++ni)
#pragma unroll
      for (int kkk = 0; kkk < 2; ++kkk)
        bfr[ni][kkk] = *(const bf16x8*)&Bs[(wn + ni * 16 + fr) * 64 + kkk * 32 + fq * 8];
#pragma unroll
    for (int mi = 0; mi < 4; ++mi)
#pragma unroll
      for (int ni = 0; ni < 4; ++ni)
#pragma unroll
        for (int kkk = 0; kkk < 2; ++kkk)
          acc[mi][ni] = __builtin_amdgcn_mfma_f32_16x16x32_bf16(af[mi][kkk], bfr[ni][kkk], acc[mi][ni], 0, 0, 0);
    __syncthreads();
  }

#pragma unroll
  for (int mi = 0; mi < 4; ++mi) {
#pragma unroll
    for (int ni = 0; ni < 4; ++ni) {
      const int mcol = m0 + wn + ni * 16 + fr;
#pragma unroll
      for (int r = 0; r < 4; ++r) {
        const int oo = o0 + wm + mi * 16 + fq * 4 + r;
        dout[((size_t)bI * 256 + oo) * MM + mcol] = acc[mi][ni][r] + bout[oo];
      }
    }
  }
}

// ---------------------------------------------------------------------------
extern "C" void kernel_launch(void* const* d_in, const int* in_sizes, int n_in,
                              void* d_out, int out_size, void* d_ws, size_t ws_size,
                              hipStream_t stream) {
  const float* img = (const float*)d_in[0];
  const float* w_qkv = (const float*)d_in[1];
  const float* w_out = (const float*)d_in[2];
  const float* b_out = (const float*)d_in[3];
  const float* rel_rows = (const float*)d_in[4];
  const float* rel_cols = (const float*)d_in[5];
  const float* gamma = (const float*)d_in[6];
  const float* beta = (const float*)d_in[7];
  float* out = (float*)d_out;

  const size_t SZ = (size_t)NH * DKC * MM;  // 16,777,216 elements
  bf16* q = (bf16*)d_ws;          // SZ bf16
  bf16* kbuf = q + SZ;            // SZ bf16: k, later reused as yh
  bf16* vbuf = kbuf + SZ;         // SZ bf16: v, later reused as contentT [b][m][512]
  bf16* imgT = vbuf + SZ;         // 8,388,608 bf16, dead after k_qkv
  // union region overlaid on imgT (alive only after k_qkv):
  float* ctxp = (float*)imgT;     // 2,097,152 f32
  float* ctx = ctxp + 2097152;    // 262,144 f32
  float* ps = ctx + 262144;       // 512
  float* ps2 = ps + 512;          // 512
  float* mu = ps2 + 512;          // 64
  float* rs = mu + 64;            // 64
  bf16* wb = imgT + 8388608;      // 393,216 bf16
  bf16* sxbuf = wb + 393216;      // SZ bf16 (33.5 MB)
  bf16* wb2 = sxbuf + SZ;         // 131,072 bf16 (w_out)
  bf16* relcb = wb2 + 131072;     // 8,192 bf16 (rel_cols padded to 128 rows)
  // total ~152 MB

  k_cvt_w<<<1536, 256, 0, stream>>>(w_qkv, wb);
  k_cvt_w2<<<512, 256, 0, stream>>>(w_out, wb2);
  k_cvt_rel<<<32, 256, 0, stream>>>(rel_cols, relcb);
  k_timg<<<dim3(64, 4, 8), 256, 0, stream>>>(img, imgT);
  k_qkv<<<dim3(32, 12, 8), 256, 0, stream>>>(wb, imgT, q, kbuf, vbuf);
  k_softmax<<<4096, 256, 0, stream>>>(kbuf);
  k_ctx_part<<<dim3(8, 64), dim3(16, 16), 0, stream>>>(kbuf, vbuf, ctxp);
  k_ctx_red<<<1024, 256, 0, stream>>>(ctxp, ctx);
  // rel-row path (kbuf dead -> becomes yh)
  k_sx<<<dim3(64, 64), dim3(16, 16), 0, stream>>>(rel_rows, q, sxbuf);
  k_yh<<<dim3(8, 4, 64), dim3(64, 4), 0, stream>>>(vbuf, sxbuf, kbuf);
  k_bnpart<<<dim3(64, 8), 256, 0, stream>>>(kbuf, ps, ps2);
  k_bnfin<<<1, 64, 0, stream>>>(ps, ps2, mu, rs);
  // v dead -> vbuf becomes contentT [b][m][512]
  k_content<<<dim3(64, 64), dim3(16, 16), 0, stream>>>(ctx, q, vbuf);
  k_relcol3<<<dim3(64, 64), 256, 0, stream>>>(q, kbuf, rel_cols ? relcb : relcb, mu, rs, gamma, beta, vbuf);
  k_final<<<dim3(32, 2, 8), 256, 0, stream>>>(wb2, vbuf, b_out, out);
}

// Round 7
// 284.807 us; speedup vs baseline: 4.3045x; 1.3151x over previous
//
#include <hip/hip_runtime.h>
#include <hip/hip_bf16.h>
#include <math.h>

// Problem constants
#define NH   64     // b*H heads
#define DKC  64     // dim per head
#define MM   4096   // x*y
#define CC   256    // img channels
#define RRN  127    // 2L-1

typedef __hip_bfloat16 bf16;
__device__ __forceinline__ float b2f(bf16 x) { return __bfloat162float(x); }
__device__ __forceinline__ bf16 f2b(float x) { return __float2bfloat16(x); }
__device__ __forceinline__ unsigned short bbits(float x) { bf16 h = f2b(x); return *(unsigned short*)&h; }
__device__ __forceinline__ float fbits(unsigned short u) { bf16 h = *(bf16*)&u; return b2f(h); }

typedef short bf16x8 __attribute__((ext_vector_type(8)));
typedef float f32x4 __attribute__((ext_vector_type(4)));
typedef unsigned short u16;
typedef u16 u16x4 __attribute__((ext_vector_type(4)));

#define AS1 __attribute__((address_space(1)))
#define AS3 __attribute__((address_space(3)))
#define GLOAD16(gp, lp) __builtin_amdgcn_global_load_lds((const AS1 void*)(gp), (AS3 void*)(lp), 16, 0, 0)

// swizzled source elem offset for staging (involution partner of FRSWZ)
__device__ __forceinline__ int swzsrc(int lane) { return 8 * ((lane & 7) ^ (lane >> 3)); }
// fragment-read elem index within a 64-elem row, row-swizzled
#define FRSWZ(kelem, row) ((kelem) ^ (((row) & 7) * 8))

// ---------------------------------------------------------------------------
// K0a/K0c/K0d/K0e: fp32 -> bf16 converts
// ---------------------------------------------------------------------------
__global__ __launch_bounds__(256) void k_cvt_w(const float* __restrict__ w, bf16* __restrict__ wb) {
  const int i = blockIdx.x * 256 + threadIdx.x;
  wb[i] = f2b(w[i]);
}
__global__ __launch_bounds__(256) void k_cvt_w2(const float* __restrict__ w, bf16* __restrict__ wb) {
  const int i = blockIdx.x * 256 + threadIdx.x;
  wb[i] = f2b(w[i]);
}
__global__ __launch_bounds__(256) void k_cvt_rel(const float* __restrict__ r, bf16* __restrict__ rb) {
  const int i = blockIdx.x * 256 + threadIdx.x;  // grid covers 8192
  rb[i] = (i < RRN * 64) ? f2b(r[i]) : f2b(0.f);
}
__global__ __launch_bounds__(256) void k_cvt_relr(const float* __restrict__ r, bf16* __restrict__ rb) {
  const int i = blockIdx.x * 256 + threadIdx.x;  // grid covers 8192, 8128 valid
  if (i < RRN * 64) rb[i] = f2b(r[i]);
}

// ---------------------------------------------------------------------------
// K0b: img fp32 [8][256][4096] -> bf16 imgT [8][4096][256]
// ---------------------------------------------------------------------------
__global__ __launch_bounds__(256) void k_timg(const float* __restrict__ img, bf16* __restrict__ imgT) {
  const int b = blockIdx.z, c0 = blockIdx.y * 64, m0 = blockIdx.x * 64;
  const int tid = threadIdx.x;
  __shared__ bf16 T[64][65];
  const float* ib = img + ((size_t)b * CC + c0) * MM + m0;
#pragma unroll
  for (int l = 0; l < 16; ++l) {
    int e = tid + l * 256;
    int cc = e >> 6, mm = e & 63;
    T[cc][mm] = f2b(ib[(size_t)cc * MM + mm]);
  }
  __syncthreads();
  bf16* ob = imgT + ((size_t)b * MM + m0) * CC + c0;
#pragma unroll
  for (int l = 0; l < 16; ++l) {
    int e = tid + l * 256;
    int mm = e >> 6, cc = e & 63;
    ob[(size_t)mm * CC + cc] = T[cc][mm];
  }
}

// ---------------------------------------------------------------------------
// K1: MFMA qkv GEMM (128x128 tile, BK=64, 4 waves), swizzled LDS
// ---------------------------------------------------------------------------
__global__ __launch_bounds__(256) void k_qkv(const bf16* __restrict__ wb, const bf16* __restrict__ imgT,
                                             bf16* __restrict__ q, bf16* __restrict__ kk, bf16* __restrict__ v) {
  const int bI = blockIdx.z;
  const int o0 = blockIdx.y * 128;
  const int m0 = blockIdx.x * 128;
  const int tid = threadIdx.x;
  const int lane = tid & 63, wid = tid >> 6;
  const int fr = lane & 15;
  const int fq = lane >> 4;
  const int wm = (wid >> 1) * 64, wn = (wid & 1) * 64;

  __shared__ __align__(16) short As[128 * 64];
  __shared__ __align__(16) short Bs[128 * 64];

  const bf16* iB = imgT + (size_t)bI * MM * CC;

  f32x4 acc[4][4];
#pragma unroll
  for (int mi = 0; mi < 4; ++mi)
#pragma unroll
    for (int ni = 0; ni < 4; ++ni) acc[mi][ni] = (f32x4){0.f, 0.f, 0.f, 0.f};

  const int srow = lane >> 3;
  const int skc = swzsrc(lane);

  for (int kt = 0; kt < 4; ++kt) {
    const int k0 = kt * 64;
#pragma unroll
    for (int cc = 0; cc < 4; ++cc) {
      const int c = wid * 4 + cc;
      const int r = c * 8 + srow;
      GLOAD16(wb + (size_t)(o0 + r) * CC + k0 + skc, &As[c * 512]);
      GLOAD16(iB + (size_t)(m0 + r) * CC + k0 + skc, &Bs[c * 512]);
    }
    __syncthreads();
    bf16x8 af[4][2], bfr[4][2];
#pragma unroll
    for (int mi = 0; mi < 4; ++mi)
#pragma unroll
      for (int kkk = 0; kkk < 2; ++kkk)
        af[mi][kkk] = *(const bf16x8*)&As[(wm + mi * 16 + fr) * 64 + FRSWZ(kkk * 32 + fq * 8, fr)];
#pragma unroll
    for (int ni = 0; ni < 4; ++ni)
#pragma unroll
      for (int kkk = 0; kkk < 2; ++kkk)
        bfr[ni][kkk] = *(const bf16x8*)&Bs[(wn + ni * 16 + fr) * 64 + FRSWZ(kkk * 32 + fq * 8, fr)];
#pragma unroll
    for (int mi = 0; mi < 4; ++mi)
#pragma unroll
      for (int ni = 0; ni < 4; ++ni)
#pragma unroll
        for (int kkk = 0; kkk < 2; ++kkk)
          acc[mi][ni] = __builtin_amdgcn_mfma_f32_16x16x32_bf16(af[mi][kkk], bfr[ni][kkk], acc[mi][ni], 0, 0, 0);
    __syncthreads();
  }

#pragma unroll
  for (int mi = 0; mi < 4; ++mi) {
#pragma unroll
    for (int ni = 0; ni < 4; ++ni) {
      const int mcol = m0 + wn + ni * 16 + fr;
#pragma unroll
      for (int r = 0; r < 4; ++r) {
        int oo = o0 + wm + mi * 16 + fq * 4 + r;
        bf16* dst;
        if (oo < 512) { dst = q; }
        else if (oo < 1024) { dst = kk; oo -= 512; }
        else { dst = v; oo -= 1024; }
        dst[((size_t)bI * 512 + oo) * MM + mcol] = f2b(acc[mi][ni][r]);
      }
    }
  }
}

// ---------------------------------------------------------------------------
// K2: in-place softmax over m=4096 per (n,d) row
// ---------------------------------------------------------------------------
__global__ __launch_bounds__(256) void k_softmax(bf16* __restrict__ kk) {
  const size_t row = blockIdx.x;
  bf16* p = kk + row * (size_t)MM;
  const int t = threadIdx.x;
  __shared__ float sred[4];
  float mx = -1e30f;
  for (int i = t; i < MM; i += 256) mx = fmaxf(mx, b2f(p[i]));
#pragma unroll
  for (int off = 32; off; off >>= 1) mx = fmaxf(mx, __shfl_down(mx, off));
  if ((t & 63) == 0) sred[t >> 6] = mx;
  __syncthreads();
  mx = fmaxf(fmaxf(sred[0], sred[1]), fmaxf(sred[2], sred[3]));
  __syncthreads();
  float s = 0.f;
  for (int i = t; i < MM; i += 256) { float e = expf(b2f(p[i]) - mx); p[i] = f2b(e); s += e; }
#pragma unroll
  for (int off = 32; off; off >>= 1) s += __shfl_down(s, off);
  if ((t & 63) == 0) sred[t >> 6] = s;
  __syncthreads();
  s = sred[0] + sred[1] + sred[2] + sred[3];
  const float inv = 1.0f / s;
  for (int i = t; i < MM; i += 256) p[i] = f2b(b2f(p[i]) * inv);
}

// ---------------------------------------------------------------------------
// K3a: MFMA ctx: part[ch][n][d][e] = sum_{m in chunk} k[n,d,m]*v[n,e,m]
// grid (4 ch, 64 n), block 256 (4 waves 2x2 over 64x64), BK=64, 16 k-iters
// ---------------------------------------------------------------------------
__global__ __launch_bounds__(256) void k_ctx2(const bf16* __restrict__ kk, const bf16* __restrict__ v,
                                              float* __restrict__ part) {
  const int ch = blockIdx.x, n = blockIdx.y;
  const int tid = threadIdx.x;
  const int lane = tid & 63, wid = tid >> 6;
  const int fr = lane & 15, fq = lane >> 4;
  const int wr = (wid >> 1) * 32, wc = (wid & 1) * 32;
  __shared__ __align__(16) short Ks[64 * 64];
  __shared__ __align__(16) short Vs[64 * 64];
  const bf16* kp = kk + (size_t)n * DKC * MM;
  const bf16* vp = v + (size_t)n * DKC * MM;
  const int srow = lane >> 3;
  const int skc = swzsrc(lane);

  f32x4 acc[2][2];
#pragma unroll
  for (int mi = 0; mi < 2; ++mi)
#pragma unroll
    for (int ni = 0; ni < 2; ++ni) acc[mi][ni] = (f32x4){0.f, 0.f, 0.f, 0.f};

  for (int t = 0; t < 16; ++t) {
    const int m0 = ch * 1024 + t * 64;
#pragma unroll
    for (int cc = 0; cc < 4; ++cc) {
      const int c = wid * 4 + cc;   // 0..15
      if (c < 8) {
        const int r = c * 8 + srow;
        GLOAD16(kp + (size_t)r * MM + m0 + skc, &Ks[c * 512]);
      } else {
        const int r = (c - 8) * 8 + srow;
        GLOAD16(vp + (size_t)r * MM + m0 + skc, &Vs[(c - 8) * 512]);
      }
    }
    __syncthreads();
    bf16x8 af[2][2], bf[2][2];
#pragma unroll
    for (int mi = 0; mi < 2; ++mi)
#pragma unroll
      for (int kkx = 0; kkx < 2; ++kkx)
        af[mi][kkx] = *(const bf16x8*)&Ks[(wr + mi * 16 + fr) * 64 + FRSWZ(kkx * 32 + fq * 8, fr)];
#pragma unroll
    for (int ni = 0; ni < 2; ++ni)
#pragma unroll
      for (int kkx = 0; kkx < 2; ++kkx)
        bf[ni][kkx] = *(const bf16x8*)&Vs[(wc + ni * 16 + fr) * 64 + FRSWZ(kkx * 32 + fq * 8, fr)];
#pragma unroll
    for (int mi = 0; mi < 2; ++mi)
#pragma unroll
      for (int ni = 0; ni < 2; ++ni)
#pragma unroll
        for (int kkx = 0; kkx < 2; ++kkx)
          acc[mi][ni] = __builtin_amdgcn_mfma_f32_16x16x32_bf16(af[mi][kkx], bf[ni][kkx], acc[mi][ni], 0, 0, 0);
    __syncthreads();
  }
  float* pb = part + ((size_t)ch * NH + n) * 4096;
#pragma unroll
  for (int mi = 0; mi < 2; ++mi)
#pragma unroll
    for (int ni = 0; ni < 2; ++ni)
#pragma unroll
      for (int r = 0; r < 4; ++r)
        pb[(wr + mi * 16 + fq * 4 + r) * 64 + wc + ni * 16 + fr] = acc[mi][ni][r];
}

// K3b: reduce 4 partials
__global__ __launch_bounds__(256) void k_ctx_red(const float* __restrict__ part, float* __restrict__ ctx) {
  const int idx = blockIdx.x * 256 + threadIdx.x;
  float s = 0.f;
#pragma unroll
  for (int c = 0; c < 4; ++c) s += part[(size_t)c * 262144 + idx];
  ctx[idx] = s;
}

// ---------------------------------------------------------------------------
// K4: MFMA content: contentT[b][m][h*64+e] = sum_d ctx[n,d,e]*q[n,d,m]
// grid (64 mt, 64 n), block 256 (4 waves 2x2). A=ctx^T (LDS), B=Qt (LDS).
// ---------------------------------------------------------------------------
__global__ __launch_bounds__(256) void k_content2(const float* __restrict__ ctx, const bf16* __restrict__ q,
                                                  bf16* __restrict__ contentT) {
  const int m0 = blockIdx.x * 64, n = blockIdx.y;
  const int bI = n >> 3, h = n & 7;
  const int tid = threadIdx.x;
  const int lane = tid & 63, wid = tid >> 6;
  const int fr = lane & 15, fq = lane >> 4;
  const int wr = (wid >> 1) * 32, wc = (wid & 1) * 32;
  __shared__ __align__(16) bf16 CT[64 * 72];   // CT[e][d^swz]
  __shared__ __align__(16) bf16 Qt[64 * 72];   // Qt[mm][d^swz]
  const float* cn = ctx + (size_t)n * 4096;
  const bf16* qn = q + (size_t)n * DKC * MM;
#pragma unroll
  for (int l = 0; l < 16; ++l) {
    int idx = tid + l * 256;
    int d = idx >> 6, e = idx & 63;
    CT[e * 72 + (d ^ (8 * (e >> 3)))] = f2b(cn[idx]);
  }
#pragma unroll
  for (int l = 0; l < 16; ++l) {
    int idx = tid + l * 256;
    int d = idx >> 6, mm = idx & 63;
    Qt[mm * 72 + (d ^ (8 * (mm >> 3)))] = qn[(size_t)d * MM + m0 + mm];
  }
  __syncthreads();
  bf16x8 af[2][2], bq[2][2];
#pragma unroll
  for (int mi = 0; mi < 2; ++mi) {
    const int row = wr + mi * 16 + fr;
    const int swz = 8 * (row >> 3);
#pragma unroll
    for (int kk = 0; kk < 2; ++kk)
      af[mi][kk] = *(const bf16x8*)&CT[row * 72 + ((kk * 32 + fq * 8) ^ swz)];
  }
#pragma unroll
  for (int ni = 0; ni < 2; ++ni) {
    const int row = wc + ni * 16 + fr;
    const int swz = 8 * (row >> 3);
#pragma unroll
    for (int kk = 0; kk < 2; ++kk)
      bq[ni][kk] = *(const bf16x8*)&Qt[row * 72 + ((kk * 32 + fq * 8) ^ swz)];
  }
  f32x4 acc[2][2];
#pragma unroll
  for (int mi = 0; mi < 2; ++mi)
#pragma unroll
    for (int ni = 0; ni < 2; ++ni) acc[mi][ni] = (f32x4){0.f, 0.f, 0.f, 0.f};
#pragma unroll
  for (int mi = 0; mi < 2; ++mi)
#pragma unroll
    for (int ni = 0; ni < 2; ++ni)
#pragma unroll
      for (int kk = 0; kk < 2; ++kk)
        acc[mi][ni] = __builtin_amdgcn_mfma_f32_16x16x32_bf16(af[mi][kk], bq[ni][kk], acc[mi][ni], 0, 0, 0);
  // D[row=e][col=mm] -> contentT[b][m0+mm][h*64+e], 4 consecutive e packed
  bf16* cb = contentT + (size_t)bI * MM * 512;
#pragma unroll
  for (int mi = 0; mi < 2; ++mi)
#pragma unroll
    for (int ni = 0; ni < 2; ++ni) {
      const int mm = wc + ni * 16 + fr;
      u16x4 pk;
#pragma unroll
      for (int r = 0; r < 4; ++r) pk[r] = bbits(acc[mi][ni][r]);
      *(u16x4*)&cb[(size_t)(m0 + mm) * 512 + h * 64 + wr + mi * 16 + fq * 4] = pk;
    }
}

// ---------------------------------------------------------------------------
// K5a: MFMA k_sx2: Sx[n][x][i][y] = sum_d relr[i+63-x][d]*q[n,d,x*64+y]
// grid (64 x, 64 n), block 256 (4 waves 2x2). A direct-from-global, B=Qt.
// ---------------------------------------------------------------------------
__global__ __launch_bounds__(256) void k_sx2(const bf16* __restrict__ relrb, const bf16* __restrict__ q,
                                             bf16* __restrict__ sx) {
  const int x = blockIdx.x, n = blockIdx.y;
  const int tid = threadIdx.x;
  const int lane = tid & 63, wid = tid >> 6;
  const int fr = lane & 15, fq = lane >> 4;
  const int wr = (wid >> 1) * 32, wc = (wid & 1) * 32;
  __shared__ __align__(16) bf16 Qt[64 * 72];   // Qt[y][d^swz]
  const size_t nb = (size_t)n * DKC * MM;
#pragma unroll
  for (int l = 0; l < 16; ++l) {
    int idx = tid + l * 256;
    int d = idx >> 6, y = idx & 63;
    Qt[y * 72 + (d ^ (8 * (y >> 3)))] = q[nb + (size_t)d * MM + x * 64 + y];
  }
  // A fragments from global: row i -> relr row i+63-x
  bf16x8 af[2][2];
#pragma unroll
  for (int mi = 0; mi < 2; ++mi) {
    const int j = wr + mi * 16 + fr + 63 - x;
#pragma unroll
    for (int kk = 0; kk < 2; ++kk)
      af[mi][kk] = *(const bf16x8*)&relrb[(size_t)j * 64 + kk * 32 + fq * 8];
  }
  __syncthreads();
  bf16x8 bq[2][2];
#pragma unroll
  for (int ni = 0; ni < 2; ++ni) {
    const int row = wc + ni * 16 + fr;
    const int swz = 8 * (row >> 3);
#pragma unroll
    for (int kk = 0; kk < 2; ++kk)
      bq[ni][kk] = *(const bf16x8*)&Qt[row * 72 + ((kk * 32 + fq * 8) ^ swz)];
  }
  f32x4 acc[2][2];
#pragma unroll
  for (int mi = 0; mi < 2; ++mi)
#pragma unroll
    for (int ni = 0; ni < 2; ++ni) acc[mi][ni] = (f32x4){0.f, 0.f, 0.f, 0.f};
#pragma unroll
  for (int mi = 0; mi < 2; ++mi)
#pragma unroll
    for (int ni = 0; ni < 2; ++ni)
#pragma unroll
      for (int kk = 0; kk < 2; ++kk)
        acc[mi][ni] = __builtin_amdgcn_mfma_f32_16x16x32_bf16(af[mi][kk], bq[ni][kk], acc[mi][ni], 0, 0, 0);
  // D[row=i][col=y] -> sx[n][x][i][y]
  bf16* sp = sx + ((size_t)(n * 64 + x)) * 4096;
#pragma unroll
  for (int mi = 0; mi < 2; ++mi)
#pragma unroll
    for (int ni = 0; ni < 2; ++ni)
#pragma unroll
      for (int r = 0; r < 4; ++r)
        sp[(wr + mi * 16 + fq * 4 + r) * 64 + wc + ni * 16 + fr] = f2b(acc[mi][ni][r]);
}

// ---------------------------------------------------------------------------
// K5b: k_yh — rel-row stage 2: Yh[n,e,x,y] = sum_i v[n,e,i*64+y]*Sx[n,x,i,y]
// ---------------------------------------------------------------------------
__global__ __launch_bounds__(256) void k_yh(const bf16* __restrict__ v, const bf16* __restrict__ sx,
                                            bf16* __restrict__ yh) {
  const int xg = blockIdx.x, et = blockIdx.y, n = blockIdx.z;
  const int y = threadIdx.x, s = threadIdx.y;
  const int eb = et * 16 + s * 4;
  const size_t nb = (size_t)n * DKC * MM;
  const bf16* vp = v + nb;
  const bf16* sp = sx + ((size_t)(n * 64 + xg * 8)) * 4096;
  float acc[4][8] = {};
#pragma unroll 4
  for (int i = 0; i < 64; ++i) {
    float vv[4], ss[8];
#pragma unroll
    for (int ee = 0; ee < 4; ++ee) vv[ee] = b2f(vp[(size_t)(eb + ee) * MM + i * 64 + y]);
#pragma unroll
    for (int xx = 0; xx < 8; ++xx) ss[xx] = b2f(sp[(size_t)(xx * 64 + i) * 64 + y]);
#pragma unroll
    for (int ee = 0; ee < 4; ++ee)
#pragma unroll
      for (int xx = 0; xx < 8; ++xx) acc[ee][xx] += vv[ee] * ss[xx];
  }
#pragma unroll
  for (int ee = 0; ee < 4; ++ee)
#pragma unroll
    for (int xx = 0; xx < 8; ++xx)
      yh[nb + (size_t)(eb + ee) * MM + (xg * 8 + xx) * 64 + y] = f2b(acc[ee][xx]);
}

// ---------------------------------------------------------------------------
// K6a: BN partial stats per (e, n-group of 8)
// ---------------------------------------------------------------------------
__global__ __launch_bounds__(256) void k_bnpart(const bf16* __restrict__ yh, float* __restrict__ ps,
                                                float* __restrict__ ps2) {
  const int e = blockIdx.x, g = blockIdx.y;
  const int t = threadIdx.x;
  float s = 0.f, s2 = 0.f;
  for (int nn = g * 8; nn < g * 8 + 8; ++nn) {
    const bf16* p = yh + (size_t)nn * DKC * MM + (size_t)e * MM;
    for (int i = t; i < MM; i += 256) { float x = b2f(p[i]); s += x; s2 += x * x; }
  }
#pragma unroll
  for (int off = 32; off; off >>= 1) { s += __shfl_down(s, off); s2 += __shfl_down(s2, off); }
  __shared__ float r1[4], r2[4];
  if ((t & 63) == 0) { r1[t >> 6] = s; r2[t >> 6] = s2; }
  __syncthreads();
  if (t == 0) {
    ps[e * 8 + g] = r1[0] + r1[1] + r1[2] + r1[3];
    ps2[e * 8 + g] = r2[0] + r2[1] + r2[2] + r2[3];
  }
}

// K6b: finalize BN stats
__global__ __launch_bounds__(64) void k_bnfin(const float* __restrict__ ps, const float* __restrict__ ps2,
                                              float* __restrict__ mu, float* __restrict__ rs) {
  const int e = threadIdx.x;
  float S = 0.f, S2 = 0.f;
#pragma unroll
  for (int g = 0; g < 8; ++g) { S += ps[e * 8 + g]; S2 += ps2[e * 8 + g]; }
  const float invN = 1.0f / (NH * (float)MM);
  float m = S * invN;
  float var = S2 * invN - m * m;
  mu[e] = m;
  rs[e] = 1.0f / sqrtf(var + 1e-5f);
}

// ---------------------------------------------------------------------------
// K7: k_relcol3 — MFMA fused rel-col per (n,x) (unchanged from round 6)
// ---------------------------------------------------------------------------
__global__ __launch_bounds__(256) void k_relcol3(const bf16* __restrict__ q, const bf16* __restrict__ yh,
                                                 const bf16* __restrict__ relcb, const float* __restrict__ mu,
                                                 const float* __restrict__ rs, const float* __restrict__ gamma,
                                                 const float* __restrict__ beta, bf16* __restrict__ contentT) {
  const int xx = blockIdx.x, n = blockIdx.y;
  const int bI = n >> 3, h = n & 7;
  const int tid = threadIdx.x;
  const int lane = tid & 63, wv = tid >> 6;
  const int fr = lane & 15, fq = lane >> 4;
  __shared__ __align__(16) bf16 smem[4608 + 9216 + 4608];
  bf16* Qt = smem;                  // [64][72] y-major, d XOR-swizzled
  bf16* Scb = smem + 4608;          // [128][72] j-major
  bf16* Ysb = smem + 4608 + 9216;   // [64][72] e-major
  bf16* DT = smem;                  // overlay on Qt after stage 1

  const size_t nb = (size_t)n * DKC * MM;

#pragma unroll
  for (int l = 0; l < 16; ++l) {
    int idx = tid + l * 256;
    int d = idx >> 6, y = idx & 63;
    Qt[y * 72 + (d ^ (8 * (y >> 3)))] = q[nb + (size_t)d * MM + xx * 64 + y];
  }
#pragma unroll
  for (int l = 0; l < 16; ++l) {
    int idx = tid + l * 256;
    int e = idx >> 6, i = idx & 63;
    float val = (b2f(yh[nb + (size_t)e * MM + xx * 64 + i]) - mu[e]) * rs[e] * gamma[e] + beta[e];
    Ysb[e * 72 + i] = f2b(val);
  }
  bf16x8 af[2][2];
#pragma unroll
  for (int mi = 0; mi < 2; ++mi)
#pragma unroll
    for (int kk = 0; kk < 2; ++kk)
      af[mi][kk] = *(const bf16x8*)&relcb[(size_t)(wv * 32 + mi * 16 + fr) * 64 + kk * 32 + fq * 8];
  __syncthreads();

  f32x4 acc1[2][4];
#pragma unroll
  for (int mi = 0; mi < 2; ++mi)
#pragma unroll
    for (int ni = 0; ni < 4; ++ni) acc1[mi][ni] = (f32x4){0.f, 0.f, 0.f, 0.f};
  bf16x8 bq[4][2];
#pragma unroll
  for (int ni = 0; ni < 4; ++ni) {
    const int row = ni * 16 + fr;
    const int swz = 8 * (row >> 3);
#pragma unroll
    for (int kk = 0; kk < 2; ++kk)
      bq[ni][kk] = *(const bf16x8*)&Qt[row * 72 + ((kk * 32 + fq * 8) ^ swz)];
  }
#pragma unroll
  for (int mi = 0; mi < 2; ++mi)
#pragma unroll
    for (int ni = 0; ni < 4; ++ni)
#pragma unroll
      for (int kk = 0; kk < 2; ++kk)
        acc1[mi][ni] = __builtin_amdgcn_mfma_f32_16x16x32_bf16(af[mi][kk], bq[ni][kk], acc1[mi][ni], 0, 0, 0);
#pragma unroll
  for (int mi = 0; mi < 2; ++mi)
#pragma unroll
    for (int ni = 0; ni < 4; ++ni)
#pragma unroll
      for (int r = 0; r < 4; ++r)
        Scb[(wv * 32 + mi * 16 + fq * 4 + r) * 72 + ni * 16 + fr] = f2b(acc1[mi][ni][r]);
  __syncthreads();

#pragma unroll
  for (int l = 0; l < 16; ++l) {
    int idx = tid + l * 256;
    int y = idx >> 6, i = idx & 63;
    DT[y * 72 + i] = Scb[(i - y + 63) * 72 + y];
  }
  __syncthreads();

  bf16x8 a2[2], bd[4][2];
#pragma unroll
  for (int kk = 0; kk < 2; ++kk)
    a2[kk] = *(const bf16x8*)&Ysb[(wv * 16 + fr) * 72 + kk * 32 + fq * 8];
#pragma unroll
  for (int ni = 0; ni < 4; ++ni)
#pragma unroll
    for (int kk = 0; kk < 2; ++kk)
      bd[ni][kk] = *(const bf16x8*)&DT[(ni * 16 + fr) * 72 + kk * 32 + fq * 8];
  f32x4 acc2[4];
#pragma unroll
  for (int ni = 0; ni < 4; ++ni) acc2[ni] = (f32x4){0.f, 0.f, 0.f, 0.f};
#pragma unroll
  for (int ni = 0; ni < 4; ++ni)
#pragma unroll
    for (int kk = 0; kk < 2; ++kk)
      acc2[ni] = __builtin_amdgcn_mfma_f32_16x16x32_bf16(a2[kk], bd[ni][kk], acc2[ni], 0, 0, 0);

  bf16* cb = contentT + (size_t)bI * MM * 512;
#pragma unroll
  for (int ni = 0; ni < 4; ++ni) {
    size_t a = (size_t)(xx * 64 + ni * 16 + fr) * 512 + h * 64 + wv * 16 + fq * 4;
    u16x4 pk = *(u16x4*)&cb[a];
#pragma unroll
    for (int r = 0; r < 4; ++r) pk[r] = bbits(fbits(pk[r]) + acc2[ni][r]);
    *(u16x4*)&cb[a] = pk;
  }
}

// ---------------------------------------------------------------------------
// K8: MFMA final GEMM, swizzled LDS
// ---------------------------------------------------------------------------
__global__ __launch_bounds__(256) void k_final(const bf16* __restrict__ wb2, const bf16* __restrict__ cT,
                                               const float* __restrict__ bout, float* __restrict__ dout) {
  const int bI = blockIdx.z;
  const int o0 = blockIdx.y * 128;
  const int m0 = blockIdx.x * 128;
  const int tid = threadIdx.x;
  const int lane = tid & 63, wid = tid >> 6;
  const int fr = lane & 15;
  const int fq = lane >> 4;
  const int wm = (wid >> 1) * 64, wn = (wid & 1) * 64;

  __shared__ __align__(16) short As[128 * 64];
  __shared__ __align__(16) short Bs[128 * 64];

  const bf16* cB = cT + (size_t)bI * MM * 512;

  f32x4 acc[4][4];
#pragma unroll
  for (int mi = 0; mi < 4; ++mi)
#pragma unroll
    for (int ni = 0; ni < 4; ++ni) acc[mi][ni] = (f32x4){0.f, 0.f, 0.f, 0.f};

  const int srow = lane >> 3;
  const int skc = swzsrc(lane);

  for (int kt = 0; kt < 8; ++kt) {
    const int k0 = kt * 64;
#pragma unroll
    for (int cc = 0; cc < 4; ++cc) {
      const int c = wid * 4 + cc;
      const int r = c * 8 + srow;
      GLOAD16(wb2 + (size_t)(o0 + r) * 512 + k0 + skc, &As[c * 512]);
      GLOAD16(cB + (size_t)(m0 + r) * 512 + k0 + skc, &Bs[c * 512]);
    }
    __syncthreads();
    bf16x8 af[4][2], bfr[4][2];
#pragma unroll
    for (int mi = 0; mi < 4; ++mi)
#pragma unroll
      for (int kkk = 0; kkk < 2; ++kkk)
        af[mi][kkk] = *(const bf16x8*)&As[(wm + mi * 16 + fr) * 64 + FRSWZ(kkk * 32 + fq * 8, fr)];
#pragma unroll
    for (int ni = 0; ni < 4; ++ni)
#pragma unroll
      for (int kkk = 0; kkk < 2; ++kkk)
        bfr[ni][kkk] = *(const bf16x8*)&Bs[(wn + ni * 16 + fr) * 64 + FRSWZ(kkk * 32 + fq * 8, fr)];
#pragma unroll
    for (int mi = 0; mi < 4; ++mi)
#pragma unroll
      for (int ni = 0; ni < 4; ++ni)
#pragma unroll
        for (int kkk = 0; kkk < 2; ++kkk)
          acc[mi][ni] = __builtin_amdgcn_mfma_f32_16x16x32_bf16(af[mi][kkk], bfr[ni][kkk], acc[mi][ni], 0, 0, 0);
    __syncthreads();
  }

#pragma unroll
  for (int mi = 0; mi < 4; ++mi) {
#pragma unroll
    for (int ni = 0; ni < 4; ++ni) {
      const int mcol = m0 + wn + ni * 16 + fr;
#pragma unroll
      for (int r = 0; r < 4; ++r) {
        const int oo = o0 + wm + mi * 16 + fq * 4 + r;
        dout[((size_t)bI * 256 + oo) * MM + mcol] = acc[mi][ni][r] + bout[oo];
      }
    }
  }
}

// ---------------------------------------------------------------------------
extern "C" void kernel_launch(void* const* d_in, const int* in_sizes, int n_in,
                              void* d_out, int out_size, void* d_ws, size_t ws_size,
                              hipStream_t stream) {
  const float* img = (const float*)d_in[0];
  const float* w_qkv = (const float*)d_in[1];
  const float* w_out = (const float*)d_in[2];
  const float* b_out = (const float*)d_in[3];
  const float* rel_rows = (const float*)d_in[4];
  const float* rel_cols = (const float*)d_in[5];
  const float* gamma = (const float*)d_in[6];
  const float* beta = (const float*)d_in[7];
  float* out = (float*)d_out;

  const size_t SZ = (size_t)NH * DKC * MM;  // 16,777,216 elements
  bf16* q = (bf16*)d_ws;          // SZ bf16
  bf16* kbuf = q + SZ;            // SZ bf16: k, later reused as yh
  bf16* vbuf = kbuf + SZ;         // SZ bf16: v, later reused as contentT [b][m][512]
  bf16* imgT = vbuf + SZ;         // 8,388,608 bf16, dead after k_qkv
  // union region overlaid on imgT (alive only after k_qkv):
  float* ctxp = (float*)imgT;     // 4*262144 f32
  float* ctx = ctxp + 4 * 262144; // 262,144 f32
  float* ps = ctx + 262144;       // 512
  float* ps2 = ps + 512;          // 512
  float* mu = ps2 + 512;          // 64
  float* rs = mu + 64;            // 64
  bf16* wb = imgT + 8388608;      // 393,216 bf16
  bf16* sxbuf = wb + 393216;      // SZ bf16 (33.5 MB)
  bf16* wb2 = sxbuf + SZ;         // 131,072 bf16 (w_out)
  bf16* relcb = wb2 + 131072;     // 8,192 bf16 (rel_cols padded to 128 rows)
  bf16* relrb = relcb + 8192;     // 8,192 bf16 (rel_rows)
  // total ~152 MB

  k_cvt_w<<<1536, 256, 0, stream>>>(w_qkv, wb);
  k_cvt_w2<<<512, 256, 0, stream>>>(w_out, wb2);
  k_cvt_rel<<<32, 256, 0, stream>>>(rel_cols, relcb);
  k_cvt_relr<<<32, 256, 0, stream>>>(rel_rows, relrb);
  k_timg<<<dim3(64, 4, 8), 256, 0, stream>>>(img, imgT);
  k_qkv<<<dim3(32, 12, 8), 256, 0, stream>>>(wb, imgT, q, kbuf, vbuf);
  k_softmax<<<4096, 256, 0, stream>>>(kbuf);
  k_ctx2<<<dim3(4, 64), 256, 0, stream>>>(kbuf, vbuf, ctxp);
  k_ctx_red<<<1024, 256, 0, stream>>>(ctxp, ctx);
  // rel-row path (kbuf dead -> becomes yh)
  k_sx2<<<dim3(64, 64), 256, 0, stream>>>(relrb, q, sxbuf);
  k_yh<<<dim3(8, 4, 64), dim3(64, 4), 0, stream>>>(vbuf, sxbuf, kbuf);
  k_bnpart<<<dim3(64, 8), 256, 0, stream>>>(kbuf, ps, ps2);
  k_bnfin<<<1, 64, 0, stream>>>(ps, ps2, mu, rs);
  // v dead -> vbuf becomes contentT [b][m][512]
  k_content2<<<dim3(64, 64), 256, 0, stream>>>(ctx, q, vbuf);
  k_relcol3<<<dim3(64, 64), 256, 0, stream>>>(q, kbuf, relcb, mu, rs, gamma, beta, vbuf);
  k_final<<<dim3(32, 2, 8), 256, 0, stream>>>(wb2, vbuf, b_out, out);
}